// Round 7
// baseline (270.845 us; speedup 1.0000x reference)
//
#include <hip/hip_runtime.h>

// KNN (k=5, LARGEST distances per faithful-to-source quirk) + gather-mean.
// x: [B=2048, 64] f32, target: [N=50000, 64] f32, out: [B, 64] f32.
//
// Tier-1 (MFMA): distance GEMM via f16 hi/lo split (error ~4e-6, fp32-grade):
//   x = hi + lo*2^-12 (lo pre-scaled by 2^12 to stay in f16 normal range)
//   dot = hh + 2^-12*(hl + lh) + 2^-24*ll   -> 8 mfma_f32_16x16x32_f16 / tile
// Selection key (min-semantics): v = dot - t2/2 (= -r2/2; min v == max dist).
// Round-7: BARRIER-FREE register-staged kernel B. Round-6 counters (VALU 46%,
// Mfma 8%, occ 40%, floor arithmetic ~60us vs 268us) => latency/barrier-bound.
// Per-lane B-fragment is only 64B/tile, so stage global->VGPR 2 tiles deep
// (named bufs, static indexing), no LDS, no __syncthreads. XCD swizzle pins
// each chunk's 32 reader-blocks to one XCD (1.7MB/XCD footprint, L2-resident).

typedef _Float16 f16x8 __attribute__((ext_vector_type(8)));
typedef float    f32x4 __attribute__((ext_vector_type(4)));

constexpr int KNN = 5;
constexpr int DD  = 64;    // feature dim
constexpr int NTT = 16;    // targets per MFMA tile
constexpr int QBB = 64;    // queries per block (4 waves x 16)

// tier-2 (VALU) constants — round-3 kernel kept as fallback
constexpr int TQ  = 4;
constexpr int QB  = 32;
constexpr int NT  = 256;
constexpr int KC  = 16;
constexpr int CH  = 16;
constexpr int BLK = 512;

__device__ __forceinline__ bool pair_gt(float ad, int ai, float bd, int bi) {
  return (ad > bd) || (ad == bd && ai < bi);
}
__device__ __forceinline__ bool pair_lt(float ad, int ai, float bd, int bi) {
  return (ad < bd) || (ad == bd && ai < bi);
}

// max-semantics sorted insert (tier-2/3 paths)
__device__ __forceinline__ void top5_insert(float d2, int idx,
    float& t0d, float& t1d, float& t2d, float& t3d, float& t4d,
    int&   t0i, int&   t1i, int&   t2i, int&   t3i, int&   t4i) {
  const bool b3 = pair_gt(d2, idx, t3d, t3i);
  const bool b2 = pair_gt(d2, idx, t2d, t2i);
  const bool b1 = pair_gt(d2, idx, t1d, t1i);
  const bool b0 = pair_gt(d2, idx, t0d, t0i);
  t4d = b3 ? t3d : d2;               t4i = b3 ? t3i : idx;
  t3d = b3 ? (b2 ? t2d : d2) : t3d;  t3i = b3 ? (b2 ? t2i : idx) : t3i;
  t2d = b2 ? (b1 ? t1d : d2) : t2d;  t2i = b2 ? (b1 ? t1i : idx) : t2i;
  t1d = b1 ? (b0 ? t0d : d2) : t1d;  t1i = b1 ? (b0 ? t0i : idx) : t1i;
  t0d = b0 ? d2 : t0d;               t0i = b0 ? idx : t0i;
}

// min-semantics UNCONDITIONAL branchless insert (tier-1 hot path).
// Sorted ascending t0<=..<=t4. Strict < keeps earlier (= smaller idx) on ties.
__device__ __forceinline__ void bot5_insert_bl(float v, int idx,
    float& t0d, float& t1d, float& t2d, float& t3d, float& t4d,
    int&   t0i, int&   t1i, int&   t2i, int&   t3i, int&   t4i) {
  const bool b0 = v < t0d;
  const bool b1 = v < t1d;
  const bool b2 = v < t2d;
  const bool b3 = v < t3d;
  const bool b4 = v < t4d;
  t4d = b3 ? t3d : (b4 ? v : t4d);  t4i = b3 ? t3i : (b4 ? idx : t4i);
  t3d = b3 ? (b2 ? t2d : v) : t3d;  t3i = b3 ? (b2 ? t2i : idx) : t3i;
  t2d = b2 ? (b1 ? t1d : v) : t2d;  t2i = b2 ? (b1 ? t1i : idx) : t2i;
  t1d = b1 ? (b0 ? t0d : v) : t1d;  t1i = b1 ? (b0 ? t0i : idx) : t1i;
  t0d = b0 ? v : t0d;               t0i = b0 ? idx : t0i;
}

// ------- Kernel A (tier-1): sqnorm into chunk-contiguous image t2c[ci][j][col] -------
__launch_bounds__(256)
__global__ void sqnorm_chunked(const float* __restrict__ tg,
                               float* __restrict__ t2c,
                               int N, int Npad, int tiles, int chnlog) {
  const int tid  = threadIdx.x;
  const int lane = tid & 63;
  const int wv   = tid >> 6;
  const int row  = blockIdx.x * 16 + wv * 4 + (lane >> 4);
  const int f4   = lane & 15;
  if (row >= Npad) return;
  float s = -1e30f;
  if (row < N) {
    const float4 v = reinterpret_cast<const float4*>(tg)[(size_t)row * 16 + f4];
    s = v.x*v.x + v.y*v.y + v.z*v.z + v.w*v.w;
    s += __shfl_xor(s, 1);
    s += __shfl_xor(s, 2);
    s += __shfl_xor(s, 4);
    s += __shfl_xor(s, 8);
  }
  if (f4 == 0) {
    const int tile = row >> 4;
    const int ci   = tile & ((1 << chnlog) - 1);
    const int j    = tile >> chnlog;
    t2c[((size_t)ci * tiles + j) * 16 + (row & 15)] = s;
  }
}

// ------- Kernel A (tier-2): linear sqnorm (pad rows -1e30) -------
__launch_bounds__(256)
__global__ void sqnorm_kernel(const float* __restrict__ tg,
                              float* __restrict__ t2, int N, int Npad) {
  const int tid  = threadIdx.x;
  const int lane = tid & 63;
  const int wv   = tid >> 6;
  const int row  = blockIdx.x * 16 + wv * 4 + (lane >> 4);
  const int f4   = lane & 15;
  if (row >= Npad) return;
  float s = -1e30f;
  if (row < N) {
    const float4 v = reinterpret_cast<const float4*>(tg)[(size_t)row * 16 + f4];
    s = v.x*v.x + v.y*v.y + v.z*v.z + v.w*v.w;
    s += __shfl_xor(s, 1);
    s += __shfl_xor(s, 2);
    s += __shfl_xor(s, 4);
    s += __shfl_xor(s, 8);
  }
  if (f4 == 0) t2[row] = s;
}

// ------------- Kernel A2: convert targets to f16 hi/lo tile image -------------
// Layout per tile (4096 B): [term(2)][kb(8)][col(16)][i(8)] f16;  k = kb*8+i.
__launch_bounds__(256)
__global__ void cvt_kernel(const float* __restrict__ tg,
                           unsigned short* __restrict__ tcvt,
                           int N, int TT) {
  const int tid  = threadIdx.x;
  const int lane = tid & 63;
  const int w    = __builtin_amdgcn_readfirstlane(tid >> 6);
  const int t    = blockIdx.x * 4 + w;          // tile index
  if (t >= TT) return;
  const int col   = lane & 15;
  const int khalf = lane >> 4;                  // 0..3
  const int row   = t * NTT + col;              // global target row
  #pragma unroll
  for (int j = 0; j < 2; ++j) {
    const int kb = khalf * 2 + j;               // 0..7
    float v[8];
    if (row < N) {
      const float4 a = *reinterpret_cast<const float4*>(tg + (size_t)row * DD + kb * 8);
      const float4 b = *reinterpret_cast<const float4*>(tg + (size_t)row * DD + kb * 8 + 4);
      v[0]=a.x; v[1]=a.y; v[2]=a.z; v[3]=a.w;
      v[4]=b.x; v[5]=b.y; v[6]=b.z; v[7]=b.w;
    } else {
      #pragma unroll
      for (int i = 0; i < 8; ++i) v[i] = 0.0f;
    }
    f16x8 hv, lv;
    #pragma unroll
    for (int i = 0; i < 8; ++i) {
      const _Float16 h = (_Float16)v[i];
      hv[i] = h;
      lv[i] = (_Float16)((v[i] - (float)h) * 4096.0f);
    }
    const size_t off = (size_t)t * 2048 + kb * 128 + col * 8;  // ushort units
    *reinterpret_cast<f16x8*>(tcvt + off)        = hv;
    *reinterpret_cast<f16x8*>(tcvt + off + 1024) = lv;
  }
}

// -------- Kernel B (MFMA, barrier-free): distances + per-(query,chunk) bottom-5 --------
#define MFMA16(A, B, C) __builtin_amdgcn_mfma_f32_16x16x32_f16((A), (B), (C), 0, 0, 0)

__launch_bounds__(256)
__global__ void knn_mfma_kernel(const float* __restrict__ x,
                                const unsigned short* __restrict__ tcvt,
                                const float* __restrict__ t2c,
                                float* __restrict__ pd,
                                int*   __restrict__ pi,
                                int tiles, int CHN) {
  const int tid  = threadIdx.x;
  const int lane = tid & 63;
  const int w    = __builtin_amdgcn_readfirstlane(tid >> 6);
  // XCD swizzle: all blocks sharing a chunk ci keep the same bid%8 -> same XCD.
  const int bid  = blockIdx.x;
  const int cpx  = CHN >> 3;                       // chunks per XCD
  const int ci   = (bid & 7) * cpx + ((bid >> 3) & (cpx - 1));
  const int qb   = bid / CHN;
  const int q0w  = qb * QBB + w * 16;              // wave's first query
  const int col  = lane & 15;
  const int kb   = lane >> 4;                      // 0..3

  // ---- A fragments: 16 queries x 64 d, f16 hi/lo, in regs all kernel ----
  f16x8 ah[2], al[2];
  #pragma unroll
  for (int c = 0; c < 2; ++c) {
    const float* xp = x + (size_t)(q0w + col) * DD + c * 32 + kb * 8;
    const float4 a = *reinterpret_cast<const float4*>(xp);
    const float4 b = *reinterpret_cast<const float4*>(xp + 4);
    float v[8] = {a.x, a.y, a.z, a.w, b.x, b.y, b.z, b.w};
    #pragma unroll
    for (int i = 0; i < 8; ++i) {
      const _Float16 h = (_Float16)v[i];
      ah[c][i] = h;
      al[c][i] = (_Float16)((v[i] - (float)h) * 4096.0f);
    }
  }

  // per-lane bottom-5 per C-reg slot (4 queries/lane)
  float td0[4], td1[4], td2[4], td3[4], td4[4];
  int   ti0[4], ti1[4], ti2[4], ti3[4], ti4[4];
  #pragma unroll
  for (int r = 0; r < 4; ++r) {
    td0[r]=td1[r]=td2[r]=td3[r]=td4[r] = 1e30f;
    ti0[r]=ti1[r]=ti2[r]=ti3[r]=ti4[r] = 0;
  }

  // per-lane fragment address: tile_base + kb*256 + col*16, reads at +0/1024/2048/3072
  const size_t step = (size_t)CHN * 4096;          // bytes per j-step
  const char*  gp   = (const char*)tcvt + (size_t)ci * 4096 + (size_t)(kb * 256 + col * 16);
  const float* tp   = t2c + (size_t)ci * tiles * 16 + col;

  // ---- prologue: register-stage tiles 0 and 1 ----
  f16x8 Ah0, Ah1, Al0, Al1, Bh0, Bh1, Bl0, Bl1;
  Ah0 = *reinterpret_cast<const f16x8*>(gp);
  Ah1 = *reinterpret_cast<const f16x8*>(gp + 1024);
  Al0 = *reinterpret_cast<const f16x8*>(gp + 2048);
  Al1 = *reinterpret_cast<const f16x8*>(gp + 3072);
  Bh0 = *reinterpret_cast<const f16x8*>(gp + step);
  Bh1 = *reinterpret_cast<const f16x8*>(gp + step + 1024);
  Bl0 = *reinterpret_cast<const f16x8*>(gp + step + 2048);
  Bl1 = *reinterpret_cast<const f16x8*>(gp + step + 3072);
  float t2A = tp[0];
  float t2B = tp[16];
  gp += 2 * step;
  tp += 32;

  int idxv = ci * NTT + col;
  const int idxstep = CHN * NTT;

  for (int t = 0; t < tiles; t += 2) {
    // ---- even tile (bufA); prefetch tile t+2 into bufA ----
    {
      const float hv = -0.5f * t2A;
      f32x4 acc_hh = {hv, hv, hv, hv};
      f32x4 acc_m  = {0.f, 0.f, 0.f, 0.f};
      f32x4 acc_ll = {0.f, 0.f, 0.f, 0.f};
      acc_hh = MFMA16(ah[0], Ah0, acc_hh);
      acc_hh = MFMA16(ah[1], Ah1, acc_hh);
      acc_m  = MFMA16(ah[0], Al0, acc_m);
      acc_m  = MFMA16(ah[1], Al1, acc_m);
      acc_m  = MFMA16(al[0], Ah0, acc_m);
      acc_m  = MFMA16(al[1], Ah1, acc_m);
      acc_ll = MFMA16(al[0], Al0, acc_ll);
      acc_ll = MFMA16(al[1], Al1, acc_ll);
      Ah0 = *reinterpret_cast<const f16x8*>(gp);          // t+2 (over-read at tail
      Ah1 = *reinterpret_cast<const f16x8*>(gp + 1024);   //  lands in ws slack)
      Al0 = *reinterpret_cast<const f16x8*>(gp + 2048);
      Al1 = *reinterpret_cast<const f16x8*>(gp + 3072);
      t2A = tp[0];
      #pragma unroll
      for (int r = 0; r < 4; ++r) {
        float v = fmaf(acc_m[r], 0x1p-12f, acc_hh[r]);
        v = fmaf(acc_ll[r], 0x1p-24f, v);                 // v = dot - t2/2
        bot5_insert_bl(v, idxv,
                       td0[r], td1[r], td2[r], td3[r], td4[r],
                       ti0[r], ti1[r], ti2[r], ti3[r], ti4[r]);
      }
      idxv += idxstep;
    }
    // ---- odd tile (bufB); prefetch tile t+3 into bufB ----
    {
      const float hv = -0.5f * t2B;
      f32x4 acc_hh = {hv, hv, hv, hv};
      f32x4 acc_m  = {0.f, 0.f, 0.f, 0.f};
      f32x4 acc_ll = {0.f, 0.f, 0.f, 0.f};
      acc_hh = MFMA16(ah[0], Bh0, acc_hh);
      acc_hh = MFMA16(ah[1], Bh1, acc_hh);
      acc_m  = MFMA16(ah[0], Bl0, acc_m);
      acc_m  = MFMA16(ah[1], Bl1, acc_m);
      acc_m  = MFMA16(al[0], Bh0, acc_m);
      acc_m  = MFMA16(al[1], Bh1, acc_m);
      acc_ll = MFMA16(al[0], Bl0, acc_ll);
      acc_ll = MFMA16(al[1], Bl1, acc_ll);
      Bh0 = *reinterpret_cast<const f16x8*>(gp + step);
      Bh1 = *reinterpret_cast<const f16x8*>(gp + step + 1024);
      Bl0 = *reinterpret_cast<const f16x8*>(gp + step + 2048);
      Bl1 = *reinterpret_cast<const f16x8*>(gp + step + 3072);
      t2B = tp[16];
      #pragma unroll
      for (int r = 0; r < 4; ++r) {
        float v = fmaf(acc_m[r], 0x1p-12f, acc_hh[r]);
        v = fmaf(acc_ll[r], 0x1p-24f, v);
        bot5_insert_bl(v, idxv,
                       td0[r], td1[r], td2[r], td3[r], td4[r],
                       ti0[r], ti1[r], ti2[r], ti3[r], ti4[r]);
      }
      idxv += idxstep;
    }
    gp += 2 * step;
    tp += 32;
  }

  // ---- merge within each 16-lane group; write NEGATED keys (max-merge reuse) ----
  #pragma unroll
  for (int r = 0; r < 4; ++r) {
    float rd[KNN]; int ri[KNN];
    #pragma unroll
    for (int rr = 0; rr < KNN; ++rr) {
      float md = td0[r]; int mi = ti0[r];
      #pragma unroll
      for (int k = 1; k < 16; k <<= 1) {
        const float od = __shfl_xor(md, k);
        const int   oi = __shfl_xor(mi, k);
        if (pair_lt(od, oi, md, mi)) { md = od; mi = oi; }
      }
      rd[rr] = md; ri[rr] = mi;
      if (ti0[r] == mi && td0[r] == md) {
        td0[r]=td1[r]; ti0[r]=ti1[r];
        td1[r]=td2[r]; ti1[r]=ti2[r];
        td2[r]=td3[r]; ti2[r]=ti3[r];
        td3[r]=td4[r]; ti3[r]=ti4[r];
        td4[r]=1e30f;  ti4[r]=0;
      }
    }
    if (col == 0) {
      const int q = q0w + (lane >> 4) * 4 + r;
      const int pbase = q * (CHN * KNN) + ci * KNN;
      #pragma unroll
      for (int rr = 0; rr < KNN; ++rr) { pd[pbase + rr] = -rd[rr]; pi[pbase + rr] = ri[rr]; }
    }
  }
}

// ---------------- Kernel C: merge partials (up to 320 cands), gather, mean ----------------
__launch_bounds__(64)
__global__ void merge_kernel(const float* __restrict__ tg,
                             const float* __restrict__ pd,
                             const int*   __restrict__ pi,
                             float* __restrict__ out, int chn) {
  const int q    = blockIdx.x;
  const int lane = threadIdx.x;   // 64 threads
  const int M    = chn * KNN;     // up to 320 candidates
  const int pb   = q * M;
  float cd[5]; int cix[5];
  #pragma unroll
  for (int s = 0; s < 5; ++s) {
    const int i = lane + s * 64;
    const bool v = i < M;
    cd[s]  = v ? pd[pb + i] : -1e30f;
    cix[s] = v ? pi[pb + i] : 0;
  }
  int sel[KNN];
  #pragma unroll
  for (int r = 0; r < KNN; ++r) {
    float md = cd[0]; int mi = cix[0];
    #pragma unroll
    for (int s = 1; s < 5; ++s)
      if (pair_gt(cd[s], cix[s], md, mi)) { md = cd[s]; mi = cix[s]; }
    #pragma unroll
    for (int k = 1; k < 64; k <<= 1) {
      const float od = __shfl_xor(md, k);
      const int   oi = __shfl_xor(mi, k);
      if (pair_gt(od, oi, md, mi)) { md = od; mi = oi; }
    }
    sel[r] = mi;
    #pragma unroll
    for (int s = 0; s < 5; ++s)
      if (cix[s] == mi && cd[s] == md) cd[s] = -1e30f;
  }
  float s = 0.0f;
  #pragma unroll
  for (int r = 0; r < KNN; ++r) s += tg[(size_t)sel[r] * DD + lane];
  out[(size_t)q * DD + lane] = s / 5.0f;
}

// ---------------- Tier-2 (round-3 VALU kernel, fallback if ws too small) ----------------
__launch_bounds__(BLK)
__global__ void knn_partial_kernel(const float* __restrict__ x,
                                   const float* __restrict__ tg,
                                   const float* __restrict__ t2w,
                                   float* __restrict__ pd,
                                   int*   __restrict__ pi,
                                   int N) {
  __shared__ float tbuf[2][KC][NT];

  const int tid  = threadIdx.x;
  const int lane = tid & 63;
  const int w    = __builtin_amdgcn_readfirstlane(tid >> 6);
  const int ci   = blockIdx.x;
  const int q0   = blockIdx.y * QB + w * TQ;
  const float* xq = x + (size_t)q0 * DD;

  float td0[TQ], td1[TQ], td2[TQ], td3[TQ], td4[TQ];
  int   ti0[TQ], ti1[TQ], ti2[TQ], ti3[TQ], ti4[TQ];
  #pragma unroll
  for (int qi = 0; qi < TQ; ++qi) {
    td0[qi]=td1[qi]=td2[qi]=td3[qi]=td4[qi] = -1e30f;
    ti0[qi]=ti1[qi]=ti2[qi]=ti3[qi]=ti4[qi] = 0;
  }

  float acc[TQ][4];
  const int total_tiles = (N + NT - 1) / NT;
  const int mytiles = (ci < total_tiles) ? ((total_tiles - 1 - ci) / CH + 1) : 0;
  const int C = mytiles * 4;

  float4 sva = make_float4(0,0,0,0), svb = make_float4(0,0,0,0);
  const int n0  = tid & 255;
  const int j40 = tid >> 8;
  const int j41 = j40 + 2;
  const float4* tgv = reinterpret_cast<const float4*>(tg);

  if (C > 0) {
    const long r0 = (long)ci * NT + n0;
    if (r0 < N) { sva = tgv[r0 * 16 + j40]; svb = tgv[r0 * 16 + j41]; }
    tbuf[0][j40*4+0][n0] = sva.x;  tbuf[0][j40*4+1][n0] = sva.y;
    tbuf[0][j40*4+2][n0] = sva.z;  tbuf[0][j40*4+3][n0] = sva.w;
    tbuf[0][j41*4+0][n0] = svb.x;  tbuf[0][j41*4+1][n0] = svb.y;
    tbuf[0][j41*4+2][n0] = svb.z;  tbuf[0][j41*4+3][n0] = svb.w;
  }
  __syncthreads();

  for (int c = 0; c < C; ++c) {
    const int b       = c & 1;
    const int kc      = c & 3;
    const int tileidx = ci + (c >> 2) * CH;
    const bool more   = (c + 1 < C);

    if (more) {
      const int gc2   = c + 1;
      const int kc2   = gc2 & 3;
      const int tile2 = ci + (gc2 >> 2) * CH;
      const long r0n  = (long)tile2 * NT + n0;
      sva = make_float4(0,0,0,0);
      svb = make_float4(0,0,0,0);
      if (r0n < N) {
        sva = tgv[r0n * 16 + kc2 * 4 + j40];
        svb = tgv[r0n * 16 + kc2 * 4 + j41];
      }
    }

    if (kc == 0) {
      #pragma unroll
      for (int qi = 0; qi < TQ; ++qi) {
        acc[qi][0]=0.f; acc[qi][1]=0.f; acc[qi][2]=0.f; acc[qi][3]=0.f;
      }
    }
    #pragma unroll
    for (int h = 0; h < 2; ++h) {
      const int dbase = kc * KC + h * 8;
      float qs[TQ][8];
      #pragma unroll
      for (int qi = 0; qi < TQ; ++qi) {
        const float4 qa = *reinterpret_cast<const float4*>(xq + qi * DD + dbase);
        const float4 qb = *reinterpret_cast<const float4*>(xq + qi * DD + dbase + 4);
        qs[qi][0]=qa.x; qs[qi][1]=qa.y; qs[qi][2]=qa.z; qs[qi][3]=qa.w;
        qs[qi][4]=qb.x; qs[qi][5]=qb.y; qs[qi][6]=qb.z; qs[qi][7]=qb.w;
      }
      #pragma unroll
      for (int dd = 0; dd < 8; ++dd) {
        const float4 tv = *reinterpret_cast<const float4*>(&tbuf[b][h*8+dd][lane*4]);
        #pragma unroll
        for (int qi = 0; qi < TQ; ++qi) {
          acc[qi][0] = fmaf(qs[qi][dd], tv.x, acc[qi][0]);
          acc[qi][1] = fmaf(qs[qi][dd], tv.y, acc[qi][1]);
          acc[qi][2] = fmaf(qs[qi][dd], tv.z, acc[qi][2]);
          acc[qi][3] = fmaf(qs[qi][dd], tv.w, acc[qi][3]);
        }
      }
    }

    if (kc == 3) {
      const int nb = tileidx * NT + lane * 4;
      const float4 t2v = *reinterpret_cast<const float4*>(t2w + nb);
      const float t2a[4] = { t2v.x, t2v.y, t2v.z, t2v.w };
      #pragma unroll
      for (int qi = 0; qi < TQ; ++qi) {
        #pragma unroll
        for (int j = 0; j < 4; ++j) {
          const float r2  = fmaf(-2.0f, acc[qi][j], t2a[j]);
          const int   idx = nb + j;
          if (idx < N && pair_gt(r2, idx, td4[qi], ti4[qi]))
            top5_insert(r2, idx,
                        td0[qi], td1[qi], td2[qi], td3[qi], td4[qi],
                        ti0[qi], ti1[qi], ti2[qi], ti3[qi], ti4[qi]);
        }
      }
    }

    if (more) {
      const int bo = (c + 1) & 1;
      tbuf[bo][j40*4+0][n0] = sva.x;  tbuf[bo][j40*4+1][n0] = sva.y;
      tbuf[bo][j40*4+2][n0] = sva.z;  tbuf[bo][j40*4+3][n0] = sva.w;
      tbuf[bo][j41*4+0][n0] = svb.x;  tbuf[bo][j41*4+1][n0] = svb.y;
      tbuf[bo][j41*4+2][n0] = svb.z;  tbuf[bo][j41*4+3][n0] = svb.w;
    }
    __syncthreads();
  }

  #pragma unroll
  for (int qi = 0; qi < TQ; ++qi) {
    float rd[KNN]; int ri[KNN];
    #pragma unroll
    for (int r = 0; r < KNN; ++r) {
      float md = td0[qi]; int mi = ti0[qi];
      #pragma unroll
      for (int k = 1; k < 64; k <<= 1) {
        const float od = __shfl_xor(md, k);
        const int   oi = __shfl_xor(mi, k);
        if (pair_gt(od, oi, md, mi)) { md = od; mi = oi; }
      }
      rd[r] = md; ri[r] = mi;
      if (ti0[qi] == mi && td0[qi] == md) {
        td0[qi]=td1[qi]; ti0[qi]=ti1[qi];
        td1[qi]=td2[qi]; ti1[qi]=ti2[qi];
        td2[qi]=td3[qi]; ti2[qi]=ti3[qi];
        td3[qi]=td4[qi]; ti3[qi]=ti4[qi];
        td4[qi]=-1e30f;  ti4[qi]=0;
      }
    }
    if (lane == 0) {
      const int pbase = (q0 + qi) * (CH * KNN) + ci * KNN;
      #pragma unroll
      for (int r = 0; r < KNN; ++r) { pd[pbase + r] = rd[r]; pi[pbase + r] = ri[r]; }
    }
  }
}

// ---------------- Tier-3 fallback ----------------
__launch_bounds__(256)
__global__ void knn_fallback(const float* __restrict__ x,
                             const float* __restrict__ tg,
                             float* __restrict__ out, int N) {
  const int q   = blockIdx.x;
  const int tid = threadIdx.x;
  __shared__ float qsh[DD];
  __shared__ float smd[KNN][256];
  __shared__ int   smi[KNN][256];
  if (tid < DD) qsh[tid] = x[(size_t)q * DD + tid];
  __syncthreads();
  float qv[DD];
  #pragma unroll
  for (int d = 0; d < DD; ++d) qv[d] = qsh[d];
  float x2 = 0.0f;
  #pragma unroll
  for (int d = 0; d < DD; ++d) x2 = fmaf(qv[d], qv[d], x2);
  float a0=-1e30f,a1=-1e30f,a2=-1e30f,a3=-1e30f,a4=-1e30f;
  int   i0=0,i1=0,i2=0,i3=0,i4=0;
  for (int n = tid; n < N; n += 256) {
    const float4* tr = reinterpret_cast<const float4*>(tg + (size_t)n * DD);
    float dot = 0.0f, tt = 0.0f;
    #pragma unroll
    for (int k = 0; k < 16; ++k) {
      const float4 tv = tr[k];
      dot = fmaf(qv[4*k+0], tv.x, dot); tt = fmaf(tv.x, tv.x, tt);
      dot = fmaf(qv[4*k+1], tv.y, dot); tt = fmaf(tv.y, tv.y, tt);
      dot = fmaf(qv[4*k+2], tv.z, dot); tt = fmaf(tv.z, tv.z, tt);
      dot = fmaf(qv[4*k+3], tv.w, dot); tt = fmaf(tv.w, tv.w, tt);
    }
    const float d2 = fmaf(-2.0f, dot, x2 + tt);
    if (pair_gt(d2, n, a4, i4))
      top5_insert(d2, n, a0,a1,a2,a3,a4, i0,i1,i2,i3,i4);
  }
  smd[0][tid]=a0; smi[0][tid]=i0;  smd[1][tid]=a1; smi[1][tid]=i1;
  smd[2][tid]=a2; smi[2][tid]=i2;  smd[3][tid]=a3; smi[3][tid]=i3;
  smd[4][tid]=a4; smi[4][tid]=i4;
  __syncthreads();
  if (tid < 64) {
    a0=a1=a2=a3=a4=-1e30f; i0=i1=i2=i3=i4=0;
    for (int src = tid; src < 256; src += 64) {
      #pragma unroll
      for (int r = 0; r < KNN; ++r) {
        const float dd2 = smd[r][src]; const int ii = smi[r][src];
        if (pair_gt(dd2, ii, a4, i4))
          top5_insert(dd2, ii, a0,a1,a2,a3,a4, i0,i1,i2,i3,i4);
      }
    }
    int sel[KNN];
    #pragma unroll
    for (int r = 0; r < KNN; ++r) {
      float md = a0; int mi = i0;
      #pragma unroll
      for (int k = 1; k < 64; k <<= 1) {
        const float od = __shfl_xor(md, k);
        const int   oi = __shfl_xor(mi, k);
        if (pair_gt(od, oi, md, mi)) { md = od; mi = oi; }
      }
      sel[r] = mi;
      if (i0 == mi && a0 == md) {
        a0=a1; i0=i1; a1=a2; i1=i2; a2=a3; i2=i3; a3=a4; i3=i4; a4=-1e30f; i4=0;
      }
    }
    float s = 0.0f;
    #pragma unroll
    for (int r = 0; r < KNN; ++r) s += tg[(size_t)sel[r] * DD + tid];
    out[(size_t)q * DD + tid] = s / 5.0f;
  }
}

extern "C" void kernel_launch(void* const* d_in, const int* in_sizes, int n_in,
                              void* d_out, int out_size, void* d_ws, size_t ws_size,
                              hipStream_t stream) {
  const float* x  = (const float*)d_in[0];
  const float* tg = (const float*)d_in[1];
  float* out = (float*)d_out;
  const int B = in_sizes[0] / DD;   // 2048
  const int N = in_sizes[1] / DD;   // 50000

  // tier-1: Npad multiple of CHN*2*16 (2-tile unrolled loop), + prefetch slack
  auto t1_need = [&](int chn, int& npad, int& tt, int& tiles) {
    const int align = chn * 2 * NTT;
    npad  = ((N + align - 1) / align) * align;
    tt    = npad / NTT;
    tiles = tt / chn;
    const size_t slack = (size_t)2 * chn * 4096 + 4096;  // tail over-read
    return (size_t)npad * 4 + (size_t)B * chn * KNN * 8 + (size_t)tt * 4096 + slack;
  };
  int Npad64, TT64, tiles64, Npad32, TT32, tiles32;
  const size_t need64 = t1_need(64, Npad64, TT64, tiles64);
  const size_t need32 = t1_need(32, Npad32, TT32, tiles32);

  int CHN = 0, Npad = 0, TT = 0, tiles = 0, chnlog = 0;
  if (ws_size >= need64)      { CHN = 64; Npad = Npad64; TT = TT64; tiles = tiles64; chnlog = 6; }
  else if (ws_size >= need32) { CHN = 32; Npad = Npad32; TT = TT32; tiles = tiles32; chnlog = 5; }

  if (CHN > 0 && (B % QBB) == 0) {
    const size_t np1 = (size_t)B * CHN * KNN;
    float*          t2c  = (float*)d_ws;
    float*          pd   = t2c + Npad;
    int*            pi   = (int*)(pd + np1);
    unsigned short* tcvt = (unsigned short*)(pi + np1);
    sqnorm_chunked<<<dim3(Npad / 16), dim3(256), 0, stream>>>(tg, t2c, N, Npad, tiles, chnlog);
    cvt_kernel<<<dim3((TT + 3) / 4), dim3(256), 0, stream>>>(tg, tcvt, N, TT);
    knn_mfma_kernel<<<dim3(CHN * (B / QBB)), dim3(256), 0, stream>>>(x, tcvt, t2c, pd, pi, tiles, CHN);
    merge_kernel<<<dim3(B), dim3(64), 0, stream>>>(tg, pd, pi, out, CHN);
    return;
  }

  // tier-2
  const int    Npad_v    = (N + NT - 1) & ~(NT - 1);
  const size_t np2       = (size_t)B * CH * KNN;
  const size_t need_valu = ((size_t)Npad_v + 2 * np2) * 4;
  if (ws_size >= need_valu && (B % QB) == 0) {
    float* t2 = (float*)d_ws;
    float* pd = t2 + Npad_v;
    int*   pi = (int*)(pd + np2);
    sqnorm_kernel<<<dim3(Npad_v / 16), dim3(256), 0, stream>>>(tg, t2, N, Npad_v);
    knn_partial_kernel<<<dim3(CH, B / QB), dim3(BLK), 0, stream>>>(x, tg, t2, pd, pi, N);
    merge_kernel<<<dim3(B), dim3(64), 0, stream>>>(tg, pd, pi, out, CH);
  } else {
    knn_fallback<<<dim3(B), dim3(256), 0, stream>>>(x, tg, out, N);
  }
}

// Round 8
// 260.628 us; speedup vs baseline: 1.0392x; 1.0392x over previous
//
#include <hip/hip_runtime.h>

// KNN (k=5, LARGEST distances per faithful-to-source quirk) + gather-mean.
// x: [B=2048, 64] f32, target: [N=50000, 64] f32, out: [B, 64] f32.
//
// Tier-1 (MFMA): distance GEMM via f16 hi/lo split:
//   x = hi + lo*2^-12 (lo pre-scaled by 2^12, f16-normal)
//   dot ~= hh + 2^-12*(hl + lh)      [ll term dropped: ~2e-6 abs, same order
//                                     as the f16 rounding of lo already present]
// Selection key (min-semantics): v = dot - t2/2  (bias -t2/2 is PRE-SCALED in
// the t2c image and folded into the hh-accumulator init; pad rows = +1e30).
// Round-8: 6 MFMA + 2 accumulators per tile (was 8+3), LDS staging (zero
// staging VGPRs), CHN=32 (4% less padding, 4 blocks/CU).

typedef _Float16 f16x8 __attribute__((ext_vector_type(8)));
typedef float    f32x4 __attribute__((ext_vector_type(4)));

constexpr int KNN = 5;
constexpr int DD  = 64;    // feature dim
constexpr int NTT = 16;    // targets per MFMA tile
constexpr int GT  = 4;     // tiles per phase (one barrier per 4 tiles)
constexpr int QBB = 64;    // queries per block (4 waves x 16)

// tier-2 (VALU) constants — round-3 kernel kept as fallback
constexpr int TQ  = 4;
constexpr int QB  = 32;
constexpr int NT  = 256;
constexpr int KC  = 16;
constexpr int CH  = 16;
constexpr int BLK = 512;

__device__ __forceinline__ bool pair_gt(float ad, int ai, float bd, int bi) {
  return (ad > bd) || (ad == bd && ai < bi);
}
__device__ __forceinline__ bool pair_lt(float ad, int ai, float bd, int bi) {
  return (ad < bd) || (ad == bd && ai < bi);
}

// max-semantics sorted insert (tier-2/3 paths)
__device__ __forceinline__ void top5_insert(float d2, int idx,
    float& t0d, float& t1d, float& t2d, float& t3d, float& t4d,
    int&   t0i, int&   t1i, int&   t2i, int&   t3i, int&   t4i) {
  const bool b3 = pair_gt(d2, idx, t3d, t3i);
  const bool b2 = pair_gt(d2, idx, t2d, t2i);
  const bool b1 = pair_gt(d2, idx, t1d, t1i);
  const bool b0 = pair_gt(d2, idx, t0d, t0i);
  t4d = b3 ? t3d : d2;               t4i = b3 ? t3i : idx;
  t3d = b3 ? (b2 ? t2d : d2) : t3d;  t3i = b3 ? (b2 ? t2i : idx) : t3i;
  t2d = b2 ? (b1 ? t1d : d2) : t2d;  t2i = b2 ? (b1 ? t1i : idx) : t2i;
  t1d = b1 ? (b0 ? t0d : d2) : t1d;  t1i = b1 ? (b0 ? t0i : idx) : t1i;
  t0d = b0 ? d2 : t0d;               t0i = b0 ? idx : t0i;
}

// min-semantics UNCONDITIONAL branchless insert (tier-1 hot path).
// Sorted ascending t0<=..<=t4. Strict < keeps earlier (= smaller idx) on ties.
__device__ __forceinline__ void bot5_insert_bl(float v, int idx,
    float& t0d, float& t1d, float& t2d, float& t3d, float& t4d,
    int&   t0i, int&   t1i, int&   t2i, int&   t3i, int&   t4i) {
  const bool b0 = v < t0d;
  const bool b1 = v < t1d;
  const bool b2 = v < t2d;
  const bool b3 = v < t3d;
  const bool b4 = v < t4d;
  t4d = b3 ? t3d : (b4 ? v : t4d);  t4i = b3 ? t3i : (b4 ? idx : t4i);
  t3d = b3 ? (b2 ? t2d : v) : t3d;  t3i = b3 ? (b2 ? t2i : idx) : t3i;
  t2d = b2 ? (b1 ? t1d : v) : t2d;  t2i = b2 ? (b1 ? t1i : idx) : t2i;
  t1d = b1 ? (b0 ? t0d : v) : t1d;  t1i = b1 ? (b0 ? t0i : idx) : t1i;
  t0d = b0 ? v : t0d;               t0i = b0 ? idx : t0i;
}

__device__ __forceinline__ void gload16(const void* g, void* l) {
  __builtin_amdgcn_global_load_lds(
      (const __attribute__((address_space(1))) unsigned int*)g,
      (__attribute__((address_space(3))) unsigned int*)l, 16, 0, 0);
}

// ------- Kernel A (tier-1): bias image t2c[ci][j][col] = -t2/2 (pads +1e30) -------
__launch_bounds__(256)
__global__ void sqnorm_chunked(const float* __restrict__ tg,
                               float* __restrict__ t2c,
                               int N, int Npad, int tiles, int chnlog) {
  const int tid  = threadIdx.x;
  const int lane = tid & 63;
  const int wv   = tid >> 6;
  const int row  = blockIdx.x * 16 + wv * 4 + (lane >> 4);
  const int f4   = lane & 15;
  if (row >= Npad) return;
  float bias = 1e30f;
  if (row < N) {
    const float4 v = reinterpret_cast<const float4*>(tg)[(size_t)row * 16 + f4];
    float s = v.x*v.x + v.y*v.y + v.z*v.z + v.w*v.w;
    s += __shfl_xor(s, 1);
    s += __shfl_xor(s, 2);
    s += __shfl_xor(s, 4);
    s += __shfl_xor(s, 8);
    bias = -0.5f * s;
  }
  if (f4 == 0) {
    const int tile = row >> 4;
    const int ci   = tile & ((1 << chnlog) - 1);
    const int j    = tile >> chnlog;
    t2c[((size_t)ci * tiles + j) * 16 + (row & 15)] = bias;
  }
}

// ------- Kernel A (tier-2): linear sqnorm (pad rows -1e30) -------
__launch_bounds__(256)
__global__ void sqnorm_kernel(const float* __restrict__ tg,
                              float* __restrict__ t2, int N, int Npad) {
  const int tid  = threadIdx.x;
  const int lane = tid & 63;
  const int wv   = tid >> 6;
  const int row  = blockIdx.x * 16 + wv * 4 + (lane >> 4);
  const int f4   = lane & 15;
  if (row >= Npad) return;
  float s = -1e30f;
  if (row < N) {
    const float4 v = reinterpret_cast<const float4*>(tg)[(size_t)row * 16 + f4];
    s = v.x*v.x + v.y*v.y + v.z*v.z + v.w*v.w;
    s += __shfl_xor(s, 1);
    s += __shfl_xor(s, 2);
    s += __shfl_xor(s, 4);
    s += __shfl_xor(s, 8);
  }
  if (f4 == 0) t2[row] = s;
}

// ------------- Kernel A2: convert targets to f16 hi/lo tile image -------------
// Layout per tile (4096 B): [term(2)][kb(8)][col(16)][i(8)] f16;  k = kb*8+i.
__launch_bounds__(256)
__global__ void cvt_kernel(const float* __restrict__ tg,
                           unsigned short* __restrict__ tcvt,
                           int N, int TT) {
  const int tid  = threadIdx.x;
  const int lane = tid & 63;
  const int w    = __builtin_amdgcn_readfirstlane(tid >> 6);
  const int t    = blockIdx.x * 4 + w;          // tile index
  if (t >= TT) return;
  const int col   = lane & 15;
  const int khalf = lane >> 4;                  // 0..3
  const int row   = t * NTT + col;              // global target row
  #pragma unroll
  for (int j = 0; j < 2; ++j) {
    const int kb = khalf * 2 + j;               // 0..7
    float v[8];
    if (row < N) {
      const float4 a = *reinterpret_cast<const float4*>(tg + (size_t)row * DD + kb * 8);
      const float4 b = *reinterpret_cast<const float4*>(tg + (size_t)row * DD + kb * 8 + 4);
      v[0]=a.x; v[1]=a.y; v[2]=a.z; v[3]=a.w;
      v[4]=b.x; v[5]=b.y; v[6]=b.z; v[7]=b.w;
    } else {
      #pragma unroll
      for (int i = 0; i < 8; ++i) v[i] = 0.0f;
    }
    f16x8 hv, lv;
    #pragma unroll
    for (int i = 0; i < 8; ++i) {
      const _Float16 h = (_Float16)v[i];
      hv[i] = h;
      lv[i] = (_Float16)((v[i] - (float)h) * 4096.0f);
    }
    const size_t off = (size_t)t * 2048 + kb * 128 + col * 8;  // ushort units
    *reinterpret_cast<f16x8*>(tcvt + off)        = hv;
    *reinterpret_cast<f16x8*>(tcvt + off + 1024) = lv;
  }
}

// ---------------- Kernel B (MFMA): distances + per-(query,chunk) bottom-5 ----------------
#define MFMA16(A, B, C) __builtin_amdgcn_mfma_f32_16x16x32_f16((A), (B), (C), 0, 0, 0)

__launch_bounds__(256)
__global__ void knn_mfma_kernel(const float* __restrict__ x,
                                const unsigned short* __restrict__ tcvt,
                                const float* __restrict__ t2c,
                                float* __restrict__ pd,
                                int*   __restrict__ pi,
                                int tiles, int CHN) {
  __shared__ unsigned short sbuf[2][GT * 2048];  // 32 KiB, double-buffered

  const int tid  = threadIdx.x;
  const int lane = tid & 63;
  const int w    = __builtin_amdgcn_readfirstlane(tid >> 6);
  const int ci   = blockIdx.x;                  // target chunk
  const int q0w  = blockIdx.y * QBB + w * 16;   // wave's first query
  const int col  = lane & 15;
  const int kb   = lane >> 4;                   // 0..3

  // ---- A fragments: 16 queries x 64 d, f16 hi/lo, in regs all kernel ----
  f16x8 ah[2], al[2];
  #pragma unroll
  for (int c = 0; c < 2; ++c) {
    const float* xp = x + (size_t)(q0w + col) * DD + c * 32 + kb * 8;
    const float4 a = *reinterpret_cast<const float4*>(xp);
    const float4 b = *reinterpret_cast<const float4*>(xp + 4);
    float v[8] = {a.x, a.y, a.z, a.w, b.x, b.y, b.z, b.w};
    #pragma unroll
    for (int i = 0; i < 8; ++i) {
      const _Float16 h = (_Float16)v[i];
      ah[c][i] = h;
      al[c][i] = (_Float16)((v[i] - (float)h) * 4096.0f);
    }
  }

  // per-lane bottom-5 per C-reg slot (4 queries/lane)
  float td0[4], td1[4], td2[4], td3[4], td4[4];
  int   ti0[4], ti1[4], ti2[4], ti3[4], ti4[4];
  #pragma unroll
  for (int r = 0; r < 4; ++r) {
    td0[r]=td1[r]=td2[r]=td3[r]=td4[r] = 1e30f;
    ti0[r]=ti1[r]=ti2[r]=ti3[r]=ti4[r] = 0;
  }

  const int NP = tiles / GT;                    // exact (tiles % GT == 0)

  // running pointers
  const size_t tstep = (size_t)CHN * 2048;      // ushorts per j-step
  const unsigned short* gsrc = tcvt + (size_t)ci * 2048 + tid * 8;
  const float* tp  = t2c + (size_t)ci * tiles * 16 + col;

  // ---- prologue: stage phase 0 + bias ----
  #pragma unroll
  for (int g = 0; g < GT; ++g)
    gload16(gsrc + (size_t)g * tstep, &sbuf[0][g * 2048 + tid * 8]);
  float t2cur[GT], t2nxt[GT];
  #pragma unroll
  for (int g = 0; g < GT; ++g) t2cur[g] = tp[g * 16];
  __syncthreads();

  const unsigned short* gp = gsrc + (size_t)GT * tstep;  // phase p+1 tiles
  const float* tpr = tp + GT * 16;                       // phase p+1 bias
  int idxv = ci * NTT + col;                             // running candidate idx
  const int idxstep = CHN * NTT;
  const int lbase = kb * 128 + col * 8;                  // ushort offset of lane frag

  for (int p = 0; p < NP; ++p) {
    const int bp = p & 1;
    // 1) stage phase p+1 (issued before compute; barrier after compute drains
    //    loads that had a full phase of compute to cover their latency)
    if (p + 1 < NP) {
      #pragma unroll
      for (int g = 0; g < GT; ++g)
        gload16(gp + (size_t)g * tstep, &sbuf[bp ^ 1][g * 2048 + tid * 8]);
      #pragma unroll
      for (int g = 0; g < GT; ++g) t2nxt[g] = tpr[g * 16];
    }
    // 2) compute phase p (GT uniform tiles, 6 MFMA each)
    #pragma unroll
    for (int g = 0; g < GT; ++g) {
      const unsigned short* tb = &sbuf[bp][g * 2048];
      const f16x8 bh0 = *reinterpret_cast<const f16x8*>(tb + lbase);
      const f16x8 bh1 = *reinterpret_cast<const f16x8*>(tb + lbase + 512);
      const f16x8 bl0 = *reinterpret_cast<const f16x8*>(tb + lbase + 1024);
      const f16x8 bl1 = *reinterpret_cast<const f16x8*>(tb + lbase + 1536);
      const float hv = t2cur[g];                // pre-scaled -t2/2
      f32x4 acc1 = {hv, hv, hv, hv};
      f32x4 acc2 = {0.f, 0.f, 0.f, 0.f};
      acc1 = MFMA16(ah[0], bh0, acc1);
      acc1 = MFMA16(ah[1], bh1, acc1);
      acc2 = MFMA16(ah[0], bl0, acc2);
      acc2 = MFMA16(ah[1], bl1, acc2);
      acc2 = MFMA16(al[0], bh0, acc2);
      acc2 = MFMA16(al[1], bh1, acc2);
      #pragma unroll
      for (int r = 0; r < 4; ++r) {
        const float v = fmaf(acc2[r], 0x1p-12f, acc1[r]);  // v = dot - t2/2
        bot5_insert_bl(v, idxv,
                       td0[r], td1[r], td2[r], td3[r], td4[r],
                       ti0[r], ti1[r], ti2[r], ti3[r], ti4[r]);
      }
      idxv += idxstep;
    }
    #pragma unroll
    for (int g = 0; g < GT; ++g) t2cur[g] = t2nxt[g];
    gp  += (size_t)GT * tstep;
    tpr += GT * 16;
    __syncthreads();
  }

  // ---- merge within each 16-lane group; write NEGATED keys (max-merge reuse) ----
  #pragma unroll
  for (int r = 0; r < 4; ++r) {
    float rd[KNN]; int ri[KNN];
    #pragma unroll
    for (int rr = 0; rr < KNN; ++rr) {
      float md = td0[r]; int mi = ti0[r];
      #pragma unroll
      for (int k = 1; k < 16; k <<= 1) {
        const float od = __shfl_xor(md, k);
        const int   oi = __shfl_xor(mi, k);
        if (pair_lt(od, oi, md, mi)) { md = od; mi = oi; }
      }
      rd[rr] = md; ri[rr] = mi;
      if (ti0[r] == mi && td0[r] == md) {
        td0[r]=td1[r]; ti0[r]=ti1[r];
        td1[r]=td2[r]; ti1[r]=ti2[r];
        td2[r]=td3[r]; ti2[r]=ti3[r];
        td3[r]=td4[r]; ti3[r]=ti4[r];
        td4[r]=1e30f;  ti4[r]=0;
      }
    }
    if (col == 0) {
      const int q = q0w + (lane >> 4) * 4 + r;
      const int pbase = q * (CHN * KNN) + ci * KNN;
      #pragma unroll
      for (int rr = 0; rr < KNN; ++rr) { pd[pbase + rr] = -rd[rr]; pi[pbase + rr] = ri[rr]; }
    }
  }
}

// ---------------- Kernel C: merge partials (up to 320 cands), gather, mean ----------------
__launch_bounds__(64)
__global__ void merge_kernel(const float* __restrict__ tg,
                             const float* __restrict__ pd,
                             const int*   __restrict__ pi,
                             float* __restrict__ out, int chn) {
  const int q    = blockIdx.x;
  const int lane = threadIdx.x;   // 64 threads
  const int M    = chn * KNN;     // up to 320 candidates
  const int pb   = q * M;
  float cd[5]; int cix[5];
  #pragma unroll
  for (int s = 0; s < 5; ++s) {
    const int i = lane + s * 64;
    const bool v = i < M;
    cd[s]  = v ? pd[pb + i] : -1e30f;
    cix[s] = v ? pi[pb + i] : 0;
  }
  int sel[KNN];
  #pragma unroll
  for (int r = 0; r < KNN; ++r) {
    float md = cd[0]; int mi = cix[0];
    #pragma unroll
    for (int s = 1; s < 5; ++s)
      if (pair_gt(cd[s], cix[s], md, mi)) { md = cd[s]; mi = cix[s]; }
    #pragma unroll
    for (int k = 1; k < 64; k <<= 1) {
      const float od = __shfl_xor(md, k);
      const int   oi = __shfl_xor(mi, k);
      if (pair_gt(od, oi, md, mi)) { md = od; mi = oi; }
    }
    sel[r] = mi;
    #pragma unroll
    for (int s = 0; s < 5; ++s)
      if (cix[s] == mi && cd[s] == md) cd[s] = -1e30f;
  }
  float s = 0.0f;
  #pragma unroll
  for (int r = 0; r < KNN; ++r) s += tg[(size_t)sel[r] * DD + lane];
  out[(size_t)q * DD + lane] = s / 5.0f;
}

// ---------------- Tier-2 (round-3 VALU kernel, fallback if ws too small) ----------------
__launch_bounds__(BLK)
__global__ void knn_partial_kernel(const float* __restrict__ x,
                                   const float* __restrict__ tg,
                                   const float* __restrict__ t2w,
                                   float* __restrict__ pd,
                                   int*   __restrict__ pi,
                                   int N) {
  __shared__ float tbuf[2][KC][NT];

  const int tid  = threadIdx.x;
  const int lane = tid & 63;
  const int w    = __builtin_amdgcn_readfirstlane(tid >> 6);
  const int ci   = blockIdx.x;
  const int q0   = blockIdx.y * QB + w * TQ;
  const float* xq = x + (size_t)q0 * DD;

  float td0[TQ], td1[TQ], td2[TQ], td3[TQ], td4[TQ];
  int   ti0[TQ], ti1[TQ], ti2[TQ], ti3[TQ], ti4[TQ];
  #pragma unroll
  for (int qi = 0; qi < TQ; ++qi) {
    td0[qi]=td1[qi]=td2[qi]=td3[qi]=td4[qi] = -1e30f;
    ti0[qi]=ti1[qi]=ti2[qi]=ti3[qi]=ti4[qi] = 0;
  }

  float acc[TQ][4];
  const int total_tiles = (N + NT - 1) / NT;
  const int mytiles = (ci < total_tiles) ? ((total_tiles - 1 - ci) / CH + 1) : 0;
  const int C = mytiles * 4;

  float4 sva = make_float4(0,0,0,0), svb = make_float4(0,0,0,0);
  const int n0  = tid & 255;
  const int j40 = tid >> 8;
  const int j41 = j40 + 2;
  const float4* tgv = reinterpret_cast<const float4*>(tg);

  if (C > 0) {
    const long r0 = (long)ci * NT + n0;
    if (r0 < N) { sva = tgv[r0 * 16 + j40]; svb = tgv[r0 * 16 + j41]; }
    tbuf[0][j40*4+0][n0] = sva.x;  tbuf[0][j40*4+1][n0] = sva.y;
    tbuf[0][j40*4+2][n0] = sva.z;  tbuf[0][j40*4+3][n0] = sva.w;
    tbuf[0][j41*4+0][n0] = svb.x;  tbuf[0][j41*4+1][n0] = svb.y;
    tbuf[0][j41*4+2][n0] = svb.z;  tbuf[0][j41*4+3][n0] = svb.w;
  }
  __syncthreads();

  for (int c = 0; c < C; ++c) {
    const int b       = c & 1;
    const int kc      = c & 3;
    const int tileidx = ci + (c >> 2) * CH;
    const bool more   = (c + 1 < C);

    if (more) {
      const int gc2   = c + 1;
      const int kc2   = gc2 & 3;
      const int tile2 = ci + (gc2 >> 2) * CH;
      const long r0n  = (long)tile2 * NT + n0;
      sva = make_float4(0,0,0,0);
      svb = make_float4(0,0,0,0);
      if (r0n < N) {
        sva = tgv[r0n * 16 + kc2 * 4 + j40];
        svb = tgv[r0n * 16 + kc2 * 4 + j41];
      }
    }

    if (kc == 0) {
      #pragma unroll
      for (int qi = 0; qi < TQ; ++qi) {
        acc[qi][0]=0.f; acc[qi][1]=0.f; acc[qi][2]=0.f; acc[qi][3]=0.f;
      }
    }
    #pragma unroll
    for (int h = 0; h < 2; ++h) {
      const int dbase = kc * KC + h * 8;
      float qs[TQ][8];
      #pragma unroll
      for (int qi = 0; qi < TQ; ++qi) {
        const float4 qa = *reinterpret_cast<const float4*>(xq + qi * DD + dbase);
        const float4 qb = *reinterpret_cast<const float4*>(xq + qi * DD + dbase + 4);
        qs[qi][0]=qa.x; qs[qi][1]=qa.y; qs[qi][2]=qa.z; qs[qi][3]=qa.w;
        qs[qi][4]=qb.x; qs[qi][5]=qb.y; qs[qi][6]=qb.z; qs[qi][7]=qb.w;
      }
      #pragma unroll
      for (int dd = 0; dd < 8; ++dd) {
        const float4 tv = *reinterpret_cast<const float4*>(&tbuf[b][h*8+dd][lane*4]);
        #pragma unroll
        for (int qi = 0; qi < TQ; ++qi) {
          acc[qi][0] = fmaf(qs[qi][dd], tv.x, acc[qi][0]);
          acc[qi][1] = fmaf(qs[qi][dd], tv.y, acc[qi][1]);
          acc[qi][2] = fmaf(qs[qi][dd], tv.z, acc[qi][2]);
          acc[qi][3] = fmaf(qs[qi][dd], tv.w, acc[qi][3]);
        }
      }
    }

    if (kc == 3) {
      const int nb = tileidx * NT + lane * 4;
      const float4 t2v = *reinterpret_cast<const float4*>(t2w + nb);
      const float t2a[4] = { t2v.x, t2v.y, t2v.z, t2v.w };
      #pragma unroll
      for (int qi = 0; qi < TQ; ++qi) {
        #pragma unroll
        for (int j = 0; j < 4; ++j) {
          const float r2  = fmaf(-2.0f, acc[qi][j], t2a[j]);
          const int   idx = nb + j;
          if (idx < N && pair_gt(r2, idx, td4[qi], ti4[qi]))
            top5_insert(r2, idx,
                        td0[qi], td1[qi], td2[qi], td3[qi], td4[qi],
                        ti0[qi], ti1[qi], ti2[qi], ti3[qi], ti4[qi]);
        }
      }
    }

    if (more) {
      const int bo = (c + 1) & 1;
      tbuf[bo][j40*4+0][n0] = sva.x;  tbuf[bo][j40*4+1][n0] = sva.y;
      tbuf[bo][j40*4+2][n0] = sva.z;  tbuf[bo][j40*4+3][n0] = sva.w;
      tbuf[bo][j41*4+0][n0] = svb.x;  tbuf[bo][j41*4+1][n0] = svb.y;
      tbuf[bo][j41*4+2][n0] = svb.z;  tbuf[bo][j41*4+3][n0] = svb.w;
    }
    __syncthreads();
  }

  #pragma unroll
  for (int qi = 0; qi < TQ; ++qi) {
    float rd[KNN]; int ri[KNN];
    #pragma unroll
    for (int r = 0; r < KNN; ++r) {
      float md = td0[qi]; int mi = ti0[qi];
      #pragma unroll
      for (int k = 1; k < 64; k <<= 1) {
        const float od = __shfl_xor(md, k);
        const int   oi = __shfl_xor(mi, k);
        if (pair_gt(od, oi, md, mi)) { md = od; mi = oi; }
      }
      rd[r] = md; ri[r] = mi;
      if (ti0[qi] == mi && td0[qi] == md) {
        td0[qi]=td1[qi]; ti0[qi]=ti1[qi];
        td1[qi]=td2[qi]; ti1[qi]=ti2[qi];
        td2[qi]=td3[qi]; ti2[qi]=ti3[qi];
        td3[qi]=td4[qi]; ti3[qi]=ti4[qi];
        td4[qi]=-1e30f;  ti4[qi]=0;
      }
    }
    if (lane == 0) {
      const int pbase = (q0 + qi) * (CH * KNN) + ci * KNN;
      #pragma unroll
      for (int r = 0; r < KNN; ++r) { pd[pbase + r] = rd[r]; pi[pbase + r] = ri[r]; }
    }
  }
}

// ---------------- Tier-3 fallback ----------------
__launch_bounds__(256)
__global__ void knn_fallback(const float* __restrict__ x,
                             const float* __restrict__ tg,
                             float* __restrict__ out, int N) {
  const int q   = blockIdx.x;
  const int tid = threadIdx.x;
  __shared__ float qsh[DD];
  __shared__ float smd[KNN][256];
  __shared__ int   smi[KNN][256];
  if (tid < DD) qsh[tid] = x[(size_t)q * DD + tid];
  __syncthreads();
  float qv[DD];
  #pragma unroll
  for (int d = 0; d < DD; ++d) qv[d] = qsh[d];
  float x2 = 0.0f;
  #pragma unroll
  for (int d = 0; d < DD; ++d) x2 = fmaf(qv[d], qv[d], x2);
  float a0=-1e30f,a1=-1e30f,a2=-1e30f,a3=-1e30f,a4=-1e30f;
  int   i0=0,i1=0,i2=0,i3=0,i4=0;
  for (int n = tid; n < N; n += 256) {
    const float4* tr = reinterpret_cast<const float4*>(tg + (size_t)n * DD);
    float dot = 0.0f, tt = 0.0f;
    #pragma unroll
    for (int k = 0; k < 16; ++k) {
      const float4 tv = tr[k];
      dot = fmaf(qv[4*k+0], tv.x, dot); tt = fmaf(tv.x, tv.x, tt);
      dot = fmaf(qv[4*k+1], tv.y, dot); tt = fmaf(tv.y, tv.y, tt);
      dot = fmaf(qv[4*k+2], tv.z, dot); tt = fmaf(tv.z, tv.z, tt);
      dot = fmaf(qv[4*k+3], tv.w, dot); tt = fmaf(tv.w, tv.w, tt);
    }
    const float d2 = fmaf(-2.0f, dot, x2 + tt);
    if (pair_gt(d2, n, a4, i4))
      top5_insert(d2, n, a0,a1,a2,a3,a4, i0,i1,i2,i3,i4);
  }
  smd[0][tid]=a0; smi[0][tid]=i0;  smd[1][tid]=a1; smi[1][tid]=i1;
  smd[2][tid]=a2; smi[2][tid]=i2;  smd[3][tid]=a3; smi[3][tid]=i3;
  smd[4][tid]=a4; smi[4][tid]=i4;
  __syncthreads();
  if (tid < 64) {
    a0=a1=a2=a3=a4=-1e30f; i0=i1=i2=i3=i4=0;
    for (int src = tid; src < 256; src += 64) {
      #pragma unroll
      for (int r = 0; r < KNN; ++r) {
        const float dd2 = smd[r][src]; const int ii = smi[r][src];
        if (pair_gt(dd2, ii, a4, i4))
          top5_insert(dd2, ii, a0,a1,a2,a3,a4, i0,i1,i2,i3,i4);
      }
    }
    int sel[KNN];
    #pragma unroll
    for (int r = 0; r < KNN; ++r) {
      float md = a0; int mi = i0;
      #pragma unroll
      for (int k = 1; k < 64; k <<= 1) {
        const float od = __shfl_xor(md, k);
        const int   oi = __shfl_xor(mi, k);
        if (pair_gt(od, oi, md, mi)) { md = od; mi = oi; }
      }
      sel[r] = mi;
      if (i0 == mi && a0 == md) {
        a0=a1; i0=i1; a1=a2; i1=i2; a2=a3; i2=i3; a3=a4; i3=i4; a4=-1e30f; i4=0;
      }
    }
    float s = 0.0f;
    #pragma unroll
    for (int r = 0; r < KNN; ++r) s += tg[(size_t)sel[r] * DD + tid];
    out[(size_t)q * DD + tid] = s / 5.0f;
  }
}

extern "C" void kernel_launch(void* const* d_in, const int* in_sizes, int n_in,
                              void* d_out, int out_size, void* d_ws, size_t ws_size,
                              hipStream_t stream) {
  const float* x  = (const float*)d_in[0];
  const float* tg = (const float*)d_in[1];
  float* out = (float*)d_out;
  const int B = in_sizes[0] / DD;   // 2048
  const int N = in_sizes[1] / DD;   // 50000

  // tier-1: Npad multiple of CHN*GT*16 for fully uniform loops
  auto t1_need = [&](int chn, int& npad, int& tt, int& tiles) {
    const int align = chn * GT * NTT;
    npad  = ((N + align - 1) / align) * align;
    tt    = npad / NTT;
    tiles = tt / chn;
    return (size_t)npad * 4 + (size_t)B * chn * KNN * 8 + (size_t)tt * 4096;
  };
  int Npad32, TT32, tiles32, Npad16, TT16, tiles16;
  const size_t need32 = t1_need(32, Npad32, TT32, tiles32);
  const size_t need16 = t1_need(16, Npad16, TT16, tiles16);

  int CHN = 0, Npad = 0, TT = 0, tiles = 0, chnlog = 0;
  if (ws_size >= need32)      { CHN = 32; Npad = Npad32; TT = TT32; tiles = tiles32; chnlog = 5; }
  else if (ws_size >= need16) { CHN = 16; Npad = Npad16; TT = TT16; tiles = tiles16; chnlog = 4; }

  if (CHN > 0 && (B % QBB) == 0) {
    const size_t np1 = (size_t)B * CHN * KNN;
    float*          t2c  = (float*)d_ws;
    float*          pd   = t2c + Npad;
    int*            pi   = (int*)(pd + np1);
    unsigned short* tcvt = (unsigned short*)(pi + np1);
    sqnorm_chunked<<<dim3(Npad / 16), dim3(256), 0, stream>>>(tg, t2c, N, Npad, tiles, chnlog);
    cvt_kernel<<<dim3((TT + 3) / 4), dim3(256), 0, stream>>>(tg, tcvt, N, TT);
    knn_mfma_kernel<<<dim3(CHN, B / QBB), dim3(256), 0, stream>>>(x, tcvt, t2c, pd, pi, tiles, CHN);
    merge_kernel<<<dim3(B), dim3(64), 0, stream>>>(tg, pd, pi, out, CHN);
    return;
  }

  // tier-2
  const int    Npad_v    = (N + NT - 1) & ~(NT - 1);
  const size_t np2       = (size_t)B * CH * KNN;
  const size_t need_valu = ((size_t)Npad_v + 2 * np2) * 4;
  if (ws_size >= need_valu && (B % QB) == 0) {
    float* t2 = (float*)d_ws;
    float* pd = t2 + Npad_v;
    int*   pi = (int*)(pd + np2);
    sqnorm_kernel<<<dim3(Npad_v / 16), dim3(256), 0, stream>>>(tg, t2, N, Npad_v);
    knn_partial_kernel<<<dim3(CH, B / QB), dim3(BLK), 0, stream>>>(x, tg, t2, pd, pi, N);
    merge_kernel<<<dim3(B), dim3(64), 0, stream>>>(tg, pd, pi, out, CH);
  } else {
    knn_fallback<<<dim3(B), dim3(256), 0, stream>>>(x, tg, out, N);
  }
}

// Round 9
// 257.170 us; speedup vs baseline: 1.0532x; 1.0134x over previous
//
#include <hip/hip_runtime.h>

// KNN (k=5, LARGEST distances per faithful-to-source quirk) + gather-mean.
// x: [B=2048, 64] f32, target: [N=50000, 64] f32, out: [B, 64] f32.
//
// Tier-1 (MFMA): distance GEMM via f16 hi/lo split:
//   x = hi + lo*2^-12 (lo pre-scaled by 2^12, f16-normal)
//   dot ~= hh + 2^-12*(hl + lh)   [ll term dropped, ~2e-6 abs]
// Selection key (min-semantics): v = dot - t2/2 (bias pre-scaled in t2c image,
// folded into hh-accumulator init; pad rows = +1e30).
// Round-9: occupancy push. r8 accounting: VALU issue ~13%/SIMD, latency-bound
// at 16 waves/CU. GT=2 (16KB LDS) + CHN=64 (2048 blocks = 8/CU) -> 32 waves/CU
// (2x latency hiding), same 25 barriers/chunk. Same-chunk blocks are 64 apart
// -> same XCD automatically (64k % 8 == 0): tcvt stays L2-local (1.6MB/XCD).

typedef _Float16 f16x8 __attribute__((ext_vector_type(8)));
typedef float    f32x4 __attribute__((ext_vector_type(4)));

constexpr int KNN = 5;
constexpr int DD  = 64;    // feature dim
constexpr int NTT = 16;    // targets per MFMA tile
constexpr int GT  = 2;     // tiles per phase (16KB LDS -> 8 blocks/CU)
constexpr int QBB = 64;    // queries per block (4 waves x 16)

// tier-2 (VALU) constants — round-3 kernel kept as fallback
constexpr int TQ  = 4;
constexpr int QB  = 32;
constexpr int NT  = 256;
constexpr int KC  = 16;
constexpr int CH  = 16;
constexpr int BLK = 512;

__device__ __forceinline__ bool pair_gt(float ad, int ai, float bd, int bi) {
  return (ad > bd) || (ad == bd && ai < bi);
}
__device__ __forceinline__ bool pair_lt(float ad, int ai, float bd, int bi) {
  return (ad < bd) || (ad == bd && ai < bi);
}

// max-semantics sorted insert (tier-2/3 paths)
__device__ __forceinline__ void top5_insert(float d2, int idx,
    float& t0d, float& t1d, float& t2d, float& t3d, float& t4d,
    int&   t0i, int&   t1i, int&   t2i, int&   t3i, int&   t4i) {
  const bool b3 = pair_gt(d2, idx, t3d, t3i);
  const bool b2 = pair_gt(d2, idx, t2d, t2i);
  const bool b1 = pair_gt(d2, idx, t1d, t1i);
  const bool b0 = pair_gt(d2, idx, t0d, t0i);
  t4d = b3 ? t3d : d2;               t4i = b3 ? t3i : idx;
  t3d = b3 ? (b2 ? t2d : d2) : t3d;  t3i = b3 ? (b2 ? t2i : idx) : t3i;
  t2d = b2 ? (b1 ? t1d : d2) : t2d;  t2i = b2 ? (b1 ? t1i : idx) : t2i;
  t1d = b1 ? (b0 ? t0d : d2) : t1d;  t1i = b1 ? (b0 ? t0i : idx) : t1i;
  t0d = b0 ? d2 : t0d;               t0i = b0 ? idx : t0i;
}

// min-semantics UNCONDITIONAL branchless insert (tier-1 hot path).
// Sorted ascending t0<=..<=t4. Strict < keeps earlier (= smaller idx) on ties.
__device__ __forceinline__ void bot5_insert_bl(float v, int idx,
    float& t0d, float& t1d, float& t2d, float& t3d, float& t4d,
    int&   t0i, int&   t1i, int&   t2i, int&   t3i, int&   t4i) {
  const bool b0 = v < t0d;
  const bool b1 = v < t1d;
  const bool b2 = v < t2d;
  const bool b3 = v < t3d;
  const bool b4 = v < t4d;
  t4d = b3 ? t3d : (b4 ? v : t4d);  t4i = b3 ? t3i : (b4 ? idx : t4i);
  t3d = b3 ? (b2 ? t2d : v) : t3d;  t3i = b3 ? (b2 ? t2i : idx) : t3i;
  t2d = b2 ? (b1 ? t1d : v) : t2d;  t2i = b2 ? (b1 ? t1i : idx) : t2i;
  t1d = b1 ? (b0 ? t0d : v) : t1d;  t1i = b1 ? (b0 ? t0i : idx) : t1i;
  t0d = b0 ? v : t0d;               t0i = b0 ? idx : t0i;
}

__device__ __forceinline__ void gload16(const void* g, void* l) {
  __builtin_amdgcn_global_load_lds(
      (const __attribute__((address_space(1))) unsigned int*)g,
      (__attribute__((address_space(3))) unsigned int*)l, 16, 0, 0);
}

// ------- Kernel A (tier-1): bias image t2c[ci][j][col] = -t2/2 (pads +1e30) -------
__launch_bounds__(256)
__global__ void sqnorm_chunked(const float* __restrict__ tg,
                               float* __restrict__ t2c,
                               int N, int Npad, int tiles, int chnlog) {
  const int tid  = threadIdx.x;
  const int lane = tid & 63;
  const int wv   = tid >> 6;
  const int row  = blockIdx.x * 16 + wv * 4 + (lane >> 4);
  const int f4   = lane & 15;
  if (row >= Npad) return;
  float bias = 1e30f;
  if (row < N) {
    const float4 v = reinterpret_cast<const float4*>(tg)[(size_t)row * 16 + f4];
    float s = v.x*v.x + v.y*v.y + v.z*v.z + v.w*v.w;
    s += __shfl_xor(s, 1);
    s += __shfl_xor(s, 2);
    s += __shfl_xor(s, 4);
    s += __shfl_xor(s, 8);
    bias = -0.5f * s;
  }
  if (f4 == 0) {
    const int tile = row >> 4;
    const int ci   = tile & ((1 << chnlog) - 1);
    const int j    = tile >> chnlog;
    t2c[((size_t)ci * tiles + j) * 16 + (row & 15)] = bias;
  }
}

// ------- Kernel A (tier-2): linear sqnorm (pad rows -1e30) -------
__launch_bounds__(256)
__global__ void sqnorm_kernel(const float* __restrict__ tg,
                              float* __restrict__ t2, int N, int Npad) {
  const int tid  = threadIdx.x;
  const int lane = tid & 63;
  const int wv   = tid >> 6;
  const int row  = blockIdx.x * 16 + wv * 4 + (lane >> 4);
  const int f4   = lane & 15;
  if (row >= Npad) return;
  float s = -1e30f;
  if (row < N) {
    const float4 v = reinterpret_cast<const float4*>(tg)[(size_t)row * 16 + f4];
    s = v.x*v.x + v.y*v.y + v.z*v.z + v.w*v.w;
    s += __shfl_xor(s, 1);
    s += __shfl_xor(s, 2);
    s += __shfl_xor(s, 4);
    s += __shfl_xor(s, 8);
  }
  if (f4 == 0) t2[row] = s;
}

// ------------- Kernel A2: convert targets to f16 hi/lo tile image -------------
// Layout per tile (4096 B): [term(2)][kb(8)][col(16)][i(8)] f16;  k = kb*8+i.
__launch_bounds__(256)
__global__ void cvt_kernel(const float* __restrict__ tg,
                           unsigned short* __restrict__ tcvt,
                           int N, int TT) {
  const int tid  = threadIdx.x;
  const int lane = tid & 63;
  const int w    = __builtin_amdgcn_readfirstlane(tid >> 6);
  const int t    = blockIdx.x * 4 + w;          // tile index
  if (t >= TT) return;
  const int col   = lane & 15;
  const int khalf = lane >> 4;                  // 0..3
  const int row   = t * NTT + col;              // global target row
  #pragma unroll
  for (int j = 0; j < 2; ++j) {
    const int kb = khalf * 2 + j;               // 0..7
    float v[8];
    if (row < N) {
      const float4 a = *reinterpret_cast<const float4*>(tg + (size_t)row * DD + kb * 8);
      const float4 b = *reinterpret_cast<const float4*>(tg + (size_t)row * DD + kb * 8 + 4);
      v[0]=a.x; v[1]=a.y; v[2]=a.z; v[3]=a.w;
      v[4]=b.x; v[5]=b.y; v[6]=b.z; v[7]=b.w;
    } else {
      #pragma unroll
      for (int i = 0; i < 8; ++i) v[i] = 0.0f;
    }
    f16x8 hv, lv;
    #pragma unroll
    for (int i = 0; i < 8; ++i) {
      const _Float16 h = (_Float16)v[i];
      hv[i] = h;
      lv[i] = (_Float16)((v[i] - (float)h) * 4096.0f);
    }
    const size_t off = (size_t)t * 2048 + kb * 128 + col * 8;  // ushort units
    *reinterpret_cast<f16x8*>(tcvt + off)        = hv;
    *reinterpret_cast<f16x8*>(tcvt + off + 1024) = lv;
  }
}

// ---------------- Kernel B (MFMA): distances + per-(query,chunk) bottom-5 ----------------
#define MFMA16(A, B, C) __builtin_amdgcn_mfma_f32_16x16x32_f16((A), (B), (C), 0, 0, 0)

__launch_bounds__(256)
__global__ void knn_mfma_kernel(const float* __restrict__ x,
                                const unsigned short* __restrict__ tcvt,
                                const float* __restrict__ t2c,
                                float* __restrict__ pd,
                                int*   __restrict__ pi,
                                int tiles, int CHN) {
  __shared__ unsigned short sbuf[2][GT * 2048];  // 16 KiB, double-buffered

  const int tid  = threadIdx.x;
  const int lane = tid & 63;
  const int w    = __builtin_amdgcn_readfirstlane(tid >> 6);
  const int ci   = blockIdx.x;                  // target chunk
  const int q0w  = blockIdx.y * QBB + w * 16;   // wave's first query
  const int col  = lane & 15;
  const int kb   = lane >> 4;                   // 0..3

  // ---- A fragments: 16 queries x 64 d, f16 hi/lo, in regs all kernel ----
  f16x8 ah[2], al[2];
  #pragma unroll
  for (int c = 0; c < 2; ++c) {
    const float* xp = x + (size_t)(q0w + col) * DD + c * 32 + kb * 8;
    const float4 a = *reinterpret_cast<const float4*>(xp);
    const float4 b = *reinterpret_cast<const float4*>(xp + 4);
    float v[8] = {a.x, a.y, a.z, a.w, b.x, b.y, b.z, b.w};
    #pragma unroll
    for (int i = 0; i < 8; ++i) {
      const _Float16 h = (_Float16)v[i];
      ah[c][i] = h;
      al[c][i] = (_Float16)((v[i] - (float)h) * 4096.0f);
    }
  }

  // per-lane bottom-5 per C-reg slot (4 queries/lane)
  float td0[4], td1[4], td2[4], td3[4], td4[4];
  int   ti0[4], ti1[4], ti2[4], ti3[4], ti4[4];
  #pragma unroll
  for (int r = 0; r < 4; ++r) {
    td0[r]=td1[r]=td2[r]=td3[r]=td4[r] = 1e30f;
    ti0[r]=ti1[r]=ti2[r]=ti3[r]=ti4[r] = 0;
  }

  const int NP = tiles / GT;                    // exact (tiles % GT == 0)

  // running pointers
  const size_t tstep = (size_t)CHN * 2048;      // ushorts per j-step
  const unsigned short* gsrc = tcvt + (size_t)ci * 2048 + tid * 8;
  const float* tp  = t2c + (size_t)ci * tiles * 16 + col;

  // ---- prologue: stage phase 0 + bias ----
  #pragma unroll
  for (int g = 0; g < GT; ++g)
    gload16(gsrc + (size_t)g * tstep, &sbuf[0][g * 2048 + tid * 8]);
  float t2cur[GT], t2nxt[GT];
  #pragma unroll
  for (int g = 0; g < GT; ++g) t2cur[g] = tp[g * 16];
  __syncthreads();

  const unsigned short* gp = gsrc + (size_t)GT * tstep;  // phase p+1 tiles
  const float* tpr = tp + GT * 16;                       // phase p+1 bias
  int idxv = ci * NTT + col;                             // running candidate idx
  const int idxstep = CHN * NTT;
  const int lbase = kb * 128 + col * 8;                  // ushort offset of lane frag

  for (int p = 0; p < NP; ++p) {
    const int bp = p & 1;
    // 1) stage phase p+1 (issued before compute; barrier after compute drains
    //    loads that had a full phase of compute to cover their latency)
    if (p + 1 < NP) {
      #pragma unroll
      for (int g = 0; g < GT; ++g)
        gload16(gp + (size_t)g * tstep, &sbuf[bp ^ 1][g * 2048 + tid * 8]);
      #pragma unroll
      for (int g = 0; g < GT; ++g) t2nxt[g] = tpr[g * 16];
    }
    // 2) compute phase p (GT uniform tiles, 6 MFMA each)
    #pragma unroll
    for (int g = 0; g < GT; ++g) {
      const unsigned short* tb = &sbuf[bp][g * 2048];
      const f16x8 bh0 = *reinterpret_cast<const f16x8*>(tb + lbase);
      const f16x8 bh1 = *reinterpret_cast<const f16x8*>(tb + lbase + 512);
      const f16x8 bl0 = *reinterpret_cast<const f16x8*>(tb + lbase + 1024);
      const f16x8 bl1 = *reinterpret_cast<const f16x8*>(tb + lbase + 1536);
      const float hv = t2cur[g];                // pre-scaled -t2/2
      f32x4 acc1 = {hv, hv, hv, hv};
      f32x4 acc2 = {0.f, 0.f, 0.f, 0.f};
      acc1 = MFMA16(ah[0], bh0, acc1);
      acc1 = MFMA16(ah[1], bh1, acc1);
      acc2 = MFMA16(ah[0], bl0, acc2);
      acc2 = MFMA16(ah[1], bl1, acc2);
      acc2 = MFMA16(al[0], bh0, acc2);
      acc2 = MFMA16(al[1], bh1, acc2);
      #pragma unroll
      for (int r = 0; r < 4; ++r) {
        const float v = fmaf(acc2[r], 0x1p-12f, acc1[r]);  // v = dot - t2/2
        bot5_insert_bl(v, idxv,
                       td0[r], td1[r], td2[r], td3[r], td4[r],
                       ti0[r], ti1[r], ti2[r], ti3[r], ti4[r]);
      }
      idxv += idxstep;
    }
    #pragma unroll
    for (int g = 0; g < GT; ++g) t2cur[g] = t2nxt[g];
    gp  += (size_t)GT * tstep;
    tpr += GT * 16;
    __syncthreads();
  }

  // ---- merge within each 16-lane group; write NEGATED keys (max-merge reuse) ----
  #pragma unroll
  for (int r = 0; r < 4; ++r) {
    float rd[KNN]; int ri[KNN];
    #pragma unroll
    for (int rr = 0; rr < KNN; ++rr) {
      float md = td0[r]; int mi = ti0[r];
      #pragma unroll
      for (int k = 1; k < 16; k <<= 1) {
        const float od = __shfl_xor(md, k);
        const int   oi = __shfl_xor(mi, k);
        if (pair_lt(od, oi, md, mi)) { md = od; mi = oi; }
      }
      rd[rr] = md; ri[rr] = mi;
      if (ti0[r] == mi && td0[r] == md) {
        td0[r]=td1[r]; ti0[r]=ti1[r];
        td1[r]=td2[r]; ti1[r]=ti2[r];
        td2[r]=td3[r]; ti2[r]=ti3[r];
        td3[r]=td4[r]; ti3[r]=ti4[r];
        td4[r]=1e30f;  ti4[r]=0;
      }
    }
    if (col == 0) {
      const int q = q0w + (lane >> 4) * 4 + r;
      const int pbase = q * (CHN * KNN) + ci * KNN;
      #pragma unroll
      for (int rr = 0; rr < KNN; ++rr) { pd[pbase + rr] = -rd[rr]; pi[pbase + rr] = ri[rr]; }
    }
  }
}

// ---------------- Kernel C: merge partials (up to 320 cands), gather, mean ----------------
__launch_bounds__(64)
__global__ void merge_kernel(const float* __restrict__ tg,
                             const float* __restrict__ pd,
                             const int*   __restrict__ pi,
                             float* __restrict__ out, int chn) {
  const int q    = blockIdx.x;
  const int lane = threadIdx.x;   // 64 threads
  const int M    = chn * KNN;     // up to 320 candidates
  const int pb   = q * M;
  float cd[5]; int cix[5];
  #pragma unroll
  for (int s = 0; s < 5; ++s) {
    const int i = lane + s * 64;
    const bool v = i < M;
    cd[s]  = v ? pd[pb + i] : -1e30f;
    cix[s] = v ? pi[pb + i] : 0;
  }
  int sel[KNN];
  #pragma unroll
  for (int r = 0; r < KNN; ++r) {
    float md = cd[0]; int mi = cix[0];
    #pragma unroll
    for (int s = 1; s < 5; ++s)
      if (pair_gt(cd[s], cix[s], md, mi)) { md = cd[s]; mi = cix[s]; }
    #pragma unroll
    for (int k = 1; k < 64; k <<= 1) {
      const float od = __shfl_xor(md, k);
      const int   oi = __shfl_xor(mi, k);
      if (pair_gt(od, oi, md, mi)) { md = od; mi = oi; }
    }
    sel[r] = mi;
    #pragma unroll
    for (int s = 0; s < 5; ++s)
      if (cix[s] == mi && cd[s] == md) cd[s] = -1e30f;
  }
  float s = 0.0f;
  #pragma unroll
  for (int r = 0; r < KNN; ++r) s += tg[(size_t)sel[r] * DD + lane];
  out[(size_t)q * DD + lane] = s / 5.0f;
}

// ---------------- Tier-2 (round-3 VALU kernel, fallback if ws too small) ----------------
__launch_bounds__(BLK)
__global__ void knn_partial_kernel(const float* __restrict__ x,
                                   const float* __restrict__ tg,
                                   const float* __restrict__ t2w,
                                   float* __restrict__ pd,
                                   int*   __restrict__ pi,
                                   int N) {
  __shared__ float tbuf[2][KC][NT];

  const int tid  = threadIdx.x;
  const int lane = tid & 63;
  const int w    = __builtin_amdgcn_readfirstlane(tid >> 6);
  const int ci   = blockIdx.x;
  const int q0   = blockIdx.y * QB + w * TQ;
  const float* xq = x + (size_t)q0 * DD;

  float td0[TQ], td1[TQ], td2[TQ], td3[TQ], td4[TQ];
  int   ti0[TQ], ti1[TQ], ti2[TQ], ti3[TQ], ti4[TQ];
  #pragma unroll
  for (int qi = 0; qi < TQ; ++qi) {
    td0[qi]=td1[qi]=td2[qi]=td3[qi]=td4[qi] = -1e30f;
    ti0[qi]=ti1[qi]=ti2[qi]=ti3[qi]=ti4[qi] = 0;
  }

  float acc[TQ][4];
  const int total_tiles = (N + NT - 1) / NT;
  const int mytiles = (ci < total_tiles) ? ((total_tiles - 1 - ci) / CH + 1) : 0;
  const int C = mytiles * 4;

  float4 sva = make_float4(0,0,0,0), svb = make_float4(0,0,0,0);
  const int n0  = tid & 255;
  const int j40 = tid >> 8;
  const int j41 = j40 + 2;
  const float4* tgv = reinterpret_cast<const float4*>(tg);

  if (C > 0) {
    const long r0 = (long)ci * NT + n0;
    if (r0 < N) { sva = tgv[r0 * 16 + j40]; svb = tgv[r0 * 16 + j41]; }
    tbuf[0][j40*4+0][n0] = sva.x;  tbuf[0][j40*4+1][n0] = sva.y;
    tbuf[0][j40*4+2][n0] = sva.z;  tbuf[0][j40*4+3][n0] = sva.w;
    tbuf[0][j41*4+0][n0] = svb.x;  tbuf[0][j41*4+1][n0] = svb.y;
    tbuf[0][j41*4+2][n0] = svb.z;  tbuf[0][j41*4+3][n0] = svb.w;
  }
  __syncthreads();

  for (int c = 0; c < C; ++c) {
    const int b       = c & 1;
    const int kc      = c & 3;
    const int tileidx = ci + (c >> 2) * CH;
    const bool more   = (c + 1 < C);

    if (more) {
      const int gc2   = c + 1;
      const int kc2   = gc2 & 3;
      const int tile2 = ci + (gc2 >> 2) * CH;
      const long r0n  = (long)tile2 * NT + n0;
      sva = make_float4(0,0,0,0);
      svb = make_float4(0,0,0,0);
      if (r0n < N) {
        sva = tgv[r0n * 16 + kc2 * 4 + j40];
        svb = tgv[r0n * 16 + kc2 * 4 + j41];
      }
    }

    if (kc == 0) {
      #pragma unroll
      for (int qi = 0; qi < TQ; ++qi) {
        acc[qi][0]=0.f; acc[qi][1]=0.f; acc[qi][2]=0.f; acc[qi][3]=0.f;
      }
    }
    #pragma unroll
    for (int h = 0; h < 2; ++h) {
      const int dbase = kc * KC + h * 8;
      float qs[TQ][8];
      #pragma unroll
      for (int qi = 0; qi < TQ; ++qi) {
        const float4 qa = *reinterpret_cast<const float4*>(xq + qi * DD + dbase);
        const float4 qb = *reinterpret_cast<const float4*>(xq + qi * DD + dbase + 4);
        qs[qi][0]=qa.x; qs[qi][1]=qa.y; qs[qi][2]=qa.z; qs[qi][3]=qa.w;
        qs[qi][4]=qb.x; qs[qi][5]=qb.y; qs[qi][6]=qb.z; qs[qi][7]=qb.w;
      }
      #pragma unroll
      for (int dd = 0; dd < 8; ++dd) {
        const float4 tv = *reinterpret_cast<const float4*>(&tbuf[b][h*8+dd][lane*4]);
        #pragma unroll
        for (int qi = 0; qi < TQ; ++qi) {
          acc[qi][0] = fmaf(qs[qi][dd], tv.x, acc[qi][0]);
          acc[qi][1] = fmaf(qs[qi][dd], tv.y, acc[qi][1]);
          acc[qi][2] = fmaf(qs[qi][dd], tv.z, acc[qi][2]);
          acc[qi][3] = fmaf(qs[qi][dd], tv.w, acc[qi][3]);
        }
      }
    }

    if (kc == 3) {
      const int nb = tileidx * NT + lane * 4;
      const float4 t2v = *reinterpret_cast<const float4*>(t2w + nb);
      const float t2a[4] = { t2v.x, t2v.y, t2v.z, t2v.w };
      #pragma unroll
      for (int qi = 0; qi < TQ; ++qi) {
        #pragma unroll
        for (int j = 0; j < 4; ++j) {
          const float r2  = fmaf(-2.0f, acc[qi][j], t2a[j]);
          const int   idx = nb + j;
          if (idx < N && pair_gt(r2, idx, td4[qi], ti4[qi]))
            top5_insert(r2, idx,
                        td0[qi], td1[qi], td2[qi], td3[qi], td4[qi],
                        ti0[qi], ti1[qi], ti2[qi], ti3[qi], ti4[qi]);
        }
      }
    }

    if (more) {
      const int bo = (c + 1) & 1;
      tbuf[bo][j40*4+0][n0] = sva.x;  tbuf[bo][j40*4+1][n0] = sva.y;
      tbuf[bo][j40*4+2][n0] = sva.z;  tbuf[bo][j40*4+3][n0] = sva.w;
      tbuf[bo][j41*4+0][n0] = svb.x;  tbuf[bo][j41*4+1][n0] = svb.y;
      tbuf[bo][j41*4+2][n0] = svb.z;  tbuf[bo][j41*4+3][n0] = svb.w;
    }
    __syncthreads();
  }

  #pragma unroll
  for (int qi = 0; qi < TQ; ++qi) {
    float rd[KNN]; int ri[KNN];
    #pragma unroll
    for (int r = 0; r < KNN; ++r) {
      float md = td0[qi]; int mi = ti0[qi];
      #pragma unroll
      for (int k = 1; k < 64; k <<= 1) {
        const float od = __shfl_xor(md, k);
        const int   oi = __shfl_xor(mi, k);
        if (pair_gt(od, oi, md, mi)) { md = od; mi = oi; }
      }
      rd[r] = md; ri[r] = mi;
      if (ti0[qi] == mi && td0[qi] == md) {
        td0[qi]=td1[qi]; ti0[qi]=ti1[qi];
        td1[qi]=td2[qi]; ti1[qi]=ti2[qi];
        td2[qi]=td3[qi]; ti2[qi]=ti3[qi];
        td3[qi]=td4[qi]; ti3[qi]=ti4[qi];
        td4[qi]=-1e30f;  ti4[qi]=0;
      }
    }
    if (lane == 0) {
      const int pbase = (q0 + qi) * (CH * KNN) + ci * KNN;
      #pragma unroll
      for (int r = 0; r < KNN; ++r) { pd[pbase + r] = rd[r]; pi[pbase + r] = ri[r]; }
    }
  }
}

// ---------------- Tier-3 fallback ----------------
__launch_bounds__(256)
__global__ void knn_fallback(const float* __restrict__ x,
                             const float* __restrict__ tg,
                             float* __restrict__ out, int N) {
  const int q   = blockIdx.x;
  const int tid = threadIdx.x;
  __shared__ float qsh[DD];
  __shared__ float smd[KNN][256];
  __shared__ int   smi[KNN][256];
  if (tid < DD) qsh[tid] = x[(size_t)q * DD + tid];
  __syncthreads();
  float qv[DD];
  #pragma unroll
  for (int d = 0; d < DD; ++d) qv[d] = qsh[d];
  float x2 = 0.0f;
  #pragma unroll
  for (int d = 0; d < DD; ++d) x2 = fmaf(qv[d], qv[d], x2);
  float a0=-1e30f,a1=-1e30f,a2=-1e30f,a3=-1e30f,a4=-1e30f;
  int   i0=0,i1=0,i2=0,i3=0,i4=0;
  for (int n = tid; n < N; n += 256) {
    const float4* tr = reinterpret_cast<const float4*>(tg + (size_t)n * DD);
    float dot = 0.0f, tt = 0.0f;
    #pragma unroll
    for (int k = 0; k < 16; ++k) {
      const float4 tv = tr[k];
      dot = fmaf(qv[4*k+0], tv.x, dot); tt = fmaf(tv.x, tv.x, tt);
      dot = fmaf(qv[4*k+1], tv.y, dot); tt = fmaf(tv.y, tv.y, tt);
      dot = fmaf(qv[4*k+2], tv.z, dot); tt = fmaf(tv.z, tv.z, tt);
      dot = fmaf(qv[4*k+3], tv.w, dot); tt = fmaf(tv.w, tv.w, tt);
    }
    const float d2 = fmaf(-2.0f, dot, x2 + tt);
    if (pair_gt(d2, n, a4, i4))
      top5_insert(d2, n, a0,a1,a2,a3,a4, i0,i1,i2,i3,i4);
  }
  smd[0][tid]=a0; smi[0][tid]=i0;  smd[1][tid]=a1; smi[1][tid]=i1;
  smd[2][tid]=a2; smi[2][tid]=i2;  smd[3][tid]=a3; smi[3][tid]=i3;
  smd[4][tid]=a4; smi[4][tid]=i4;
  __syncthreads();
  if (tid < 64) {
    a0=a1=a2=a3=a4=-1e30f; i0=i1=i2=i3=i4=0;
    for (int src = tid; src < 256; src += 64) {
      #pragma unroll
      for (int r = 0; r < KNN; ++r) {
        const float dd2 = smd[r][src]; const int ii = smi[r][src];
        if (pair_gt(dd2, ii, a4, i4))
          top5_insert(dd2, ii, a0,a1,a2,a3,a4, i0,i1,i2,i3,i4);
      }
    }
    int sel[KNN];
    #pragma unroll
    for (int r = 0; r < KNN; ++r) {
      float md = a0; int mi = i0;
      #pragma unroll
      for (int k = 1; k < 64; k <<= 1) {
        const float od = __shfl_xor(md, k);
        const int   oi = __shfl_xor(mi, k);
        if (pair_gt(od, oi, md, mi)) { md = od; mi = oi; }
      }
      sel[r] = mi;
      if (i0 == mi && a0 == md) {
        a0=a1; i0=i1; a1=a2; i1=i2; a2=a3; i2=i3; a3=a4; i3=i4; a4=-1e30f; i4=0;
      }
    }
    float s = 0.0f;
    #pragma unroll
    for (int r = 0; r < KNN; ++r) s += tg[(size_t)sel[r] * DD + tid];
    out[(size_t)q * DD + tid] = s / 5.0f;
  }
}

extern "C" void kernel_launch(void* const* d_in, const int* in_sizes, int n_in,
                              void* d_out, int out_size, void* d_ws, size_t ws_size,
                              hipStream_t stream) {
  const float* x  = (const float*)d_in[0];
  const float* tg = (const float*)d_in[1];
  float* out = (float*)d_out;
  const int B = in_sizes[0] / DD;   // 2048
  const int N = in_sizes[1] / DD;   // 50000

  // tier-1: Npad multiple of CHN*GT*16 for fully uniform loops
  auto t1_need = [&](int chn, int& npad, int& tt, int& tiles) {
    const int align = chn * GT * NTT;
    npad  = ((N + align - 1) / align) * align;
    tt    = npad / NTT;
    tiles = tt / chn;
    return (size_t)npad * 4 + (size_t)B * chn * KNN * 8 + (size_t)tt * 4096;
  };
  int Npad64, TT64, tiles64, Npad32, TT32, tiles32;
  const size_t need64 = t1_need(64, Npad64, TT64, tiles64);
  const size_t need32 = t1_need(32, Npad32, TT32, tiles32);

  int CHN = 0, Npad = 0, TT = 0, tiles = 0, chnlog = 0;
  if (ws_size >= need64)      { CHN = 64; Npad = Npad64; TT = TT64; tiles = tiles64; chnlog = 6; }
  else if (ws_size >= need32) { CHN = 32; Npad = Npad32; TT = TT32; tiles = tiles32; chnlog = 5; }

  if (CHN > 0 && (B % QBB) == 0) {
    const size_t np1 = (size_t)B * CHN * KNN;
    float*          t2c  = (float*)d_ws;
    float*          pd   = t2c + Npad;
    int*            pi   = (int*)(pd + np1);
    unsigned short* tcvt = (unsigned short*)(pi + np1);
    sqnorm_chunked<<<dim3(Npad / 16), dim3(256), 0, stream>>>(tg, t2c, N, Npad, tiles, chnlog);
    cvt_kernel<<<dim3((TT + 3) / 4), dim3(256), 0, stream>>>(tg, tcvt, N, TT);
    knn_mfma_kernel<<<dim3(CHN, B / QBB), dim3(256), 0, stream>>>(x, tcvt, t2c, pd, pi, tiles, CHN);
    merge_kernel<<<dim3(B), dim3(64), 0, stream>>>(tg, pd, pi, out, CHN);
    return;
  }

  // tier-2
  const int    Npad_v    = (N + NT - 1) & ~(NT - 1);
  const size_t np2       = (size_t)B * CH * KNN;
  const size_t need_valu = ((size_t)Npad_v + 2 * np2) * 4;
  if (ws_size >= need_valu && (B % QB) == 0) {
    float* t2 = (float*)d_ws;
    float* pd = t2 + Npad_v;
    int*   pi = (int*)(pd + np2);
    sqnorm_kernel<<<dim3(Npad_v / 16), dim3(256), 0, stream>>>(tg, t2, N, Npad_v);
    knn_partial_kernel<<<dim3(CH, B / QB), dim3(BLK), 0, stream>>>(x, tg, t2, pd, pi, N);
    merge_kernel<<<dim3(B), dim3(64), 0, stream>>>(tg, pd, pi, out, CH);
  } else {
    knn_fallback<<<dim3(B), dim3(256), 0, stream>>>(x, tg, out, N);
  }
}

// Round 10
// 100.016 us; speedup vs baseline: 2.7080x; 2.5713x over previous
//
#include <hip/hip_runtime.h>

// KNN (k=5, LARGEST distances per faithful-to-source quirk) + gather-mean.
// x: [B=2048, 64] f32, target: [N=50000, 64] f32, out: [B, 64] f32.
//
// Tier-1 (MFMA): distance GEMM via f16 hi/lo split:
//   x = hi + lo*2^-12 (lo pre-scaled by 2^12, f16-normal)
//   dot ~= hh + 2^-12*(hl + lh)
// Selection key: v = dot - t2/2 (min == farthest), mapped monotonically to u32,
// low mantissa bits replaced by the wave-uniform tile counter j. Top-5 is then
// a 9-op v_min_u32/v_max_u32 insertion network: no compares, no index regs.
// idx reconstructed from (key & jmask) in the cold merge; global idx
// = j*(CHN*16)+ci*16+col is monotone in j, so embedded-j ties reproduce exact
// smaller-index-first semantics. Quantization: 2^-17 relative (same order as
// the accepted hi/lo numeric error).
// Round-10 rationale: r6-r9 (four different schedules) all ~260us with
// per-SIMD VALU issue ~14% (CU-OR counters: 46% VALU / 6.3% Mfma). The only
// untouched lever was per-candidate VALU count: 23 -> 14.

typedef _Float16 f16x8 __attribute__((ext_vector_type(8)));
typedef float    f32x4 __attribute__((ext_vector_type(4)));

constexpr int KNN = 5;
constexpr int DD  = 64;    // feature dim
constexpr int NTT = 16;    // targets per MFMA tile
constexpr int GT  = 2;     // tiles per phase (16KB LDS)
constexpr int QBB = 64;    // queries per block (4 waves x 16)

// tier-2 (VALU) constants — round-3 kernel kept as fallback
constexpr int TQ  = 4;
constexpr int QB  = 32;
constexpr int NT  = 256;
constexpr int KC  = 16;
constexpr int CH  = 16;
constexpr int BLK = 512;

__device__ __forceinline__ bool pair_gt(float ad, int ai, float bd, int bi) {
  return (ad > bd) || (ad == bd && ai < bi);
}
__device__ __forceinline__ bool pair_lt_u(unsigned ad, int ai, unsigned bd, int bi) {
  return (ad < bd) || (ad == bd && ai < bi);
}

// max-semantics sorted insert (tier-2/3 paths)
__device__ __forceinline__ void top5_insert(float d2, int idx,
    float& t0d, float& t1d, float& t2d, float& t3d, float& t4d,
    int&   t0i, int&   t1i, int&   t2i, int&   t3i, int&   t4i) {
  const bool b3 = pair_gt(d2, idx, t3d, t3i);
  const bool b2 = pair_gt(d2, idx, t2d, t2i);
  const bool b1 = pair_gt(d2, idx, t1d, t1i);
  const bool b0 = pair_gt(d2, idx, t0d, t0i);
  t4d = b3 ? t3d : d2;               t4i = b3 ? t3i : idx;
  t3d = b3 ? (b2 ? t2d : d2) : t3d;  t3i = b3 ? (b2 ? t2i : idx) : t3i;
  t2d = b2 ? (b1 ? t1d : d2) : t2d;  t2i = b2 ? (b1 ? t1i : idx) : t2i;
  t1d = b1 ? (b0 ? t0d : d2) : t1d;  t1i = b1 ? (b0 ? t0i : idx) : t1i;
  t0d = b0 ? d2 : t0d;               t0i = b0 ? idx : t0i;
}

// 9-op min/max insertion into ascending sorted 5 (tier-1 hot path, u32 keys)
__device__ __forceinline__ void ins5_u32(unsigned c,
    unsigned& a0, unsigned& a1, unsigned& a2, unsigned& a3, unsigned& a4) {
  unsigned t;
  t = min(a0, c); c = max(a0, c); a0 = t;
  t = min(a1, c); c = max(a1, c); a1 = t;
  t = min(a2, c); c = max(a2, c); a2 = t;
  t = min(a3, c); c = max(a3, c); a3 = t;
  a4 = min(a4, c);
}

__device__ __forceinline__ void gload16(const void* g, void* l) {
  __builtin_amdgcn_global_load_lds(
      (const __attribute__((address_space(1))) unsigned int*)g,
      (__attribute__((address_space(3))) unsigned int*)l, 16, 0, 0);
}

// ------- Kernel A (tier-1): bias image t2c[ci][j][col] = -t2/2 (pads +1e30) -------
__launch_bounds__(256)
__global__ void sqnorm_chunked(const float* __restrict__ tg,
                               float* __restrict__ t2c,
                               int N, int Npad, int tiles, int chnlog) {
  const int tid  = threadIdx.x;
  const int lane = tid & 63;
  const int wv   = tid >> 6;
  const int row  = blockIdx.x * 16 + wv * 4 + (lane >> 4);
  const int f4   = lane & 15;
  if (row >= Npad) return;
  float bias = 1e30f;
  if (row < N) {
    const float4 v = reinterpret_cast<const float4*>(tg)[(size_t)row * 16 + f4];
    float s = v.x*v.x + v.y*v.y + v.z*v.z + v.w*v.w;
    s += __shfl_xor(s, 1);
    s += __shfl_xor(s, 2);
    s += __shfl_xor(s, 4);
    s += __shfl_xor(s, 8);
    bias = -0.5f * s;
  }
  if (f4 == 0) {
    const int tile = row >> 4;
    const int ci   = tile & ((1 << chnlog) - 1);
    const int j    = tile >> chnlog;
    t2c[((size_t)ci * tiles + j) * 16 + (row & 15)] = bias;
  }
}

// ------- Kernel A (tier-2): linear sqnorm (pad rows -1e30) -------
__launch_bounds__(256)
__global__ void sqnorm_kernel(const float* __restrict__ tg,
                              float* __restrict__ t2, int N, int Npad) {
  const int tid  = threadIdx.x;
  const int lane = tid & 63;
  const int wv   = tid >> 6;
  const int row  = blockIdx.x * 16 + wv * 4 + (lane >> 4);
  const int f4   = lane & 15;
  if (row >= Npad) return;
  float s = -1e30f;
  if (row < N) {
    const float4 v = reinterpret_cast<const float4*>(tg)[(size_t)row * 16 + f4];
    s = v.x*v.x + v.y*v.y + v.z*v.z + v.w*v.w;
    s += __shfl_xor(s, 1);
    s += __shfl_xor(s, 2);
    s += __shfl_xor(s, 4);
    s += __shfl_xor(s, 8);
  }
  if (f4 == 0) t2[row] = s;
}

// ------------- Kernel A2: convert targets to f16 hi/lo tile image -------------
// Layout per tile (4096 B): [term(2)][kb(8)][col(16)][i(8)] f16;  k = kb*8+i.
__launch_bounds__(256)
__global__ void cvt_kernel(const float* __restrict__ tg,
                           unsigned short* __restrict__ tcvt,
                           int N, int TT) {
  const int tid  = threadIdx.x;
  const int lane = tid & 63;
  const int w    = __builtin_amdgcn_readfirstlane(tid >> 6);
  const int t    = blockIdx.x * 4 + w;          // tile index
  if (t >= TT) return;
  const int col   = lane & 15;
  const int khalf = lane >> 4;                  // 0..3
  const int row   = t * NTT + col;              // global target row
  #pragma unroll
  for (int j = 0; j < 2; ++j) {
    const int kb = khalf * 2 + j;               // 0..7
    float v[8];
    if (row < N) {
      const float4 a = *reinterpret_cast<const float4*>(tg + (size_t)row * DD + kb * 8);
      const float4 b = *reinterpret_cast<const float4*>(tg + (size_t)row * DD + kb * 8 + 4);
      v[0]=a.x; v[1]=a.y; v[2]=a.z; v[3]=a.w;
      v[4]=b.x; v[5]=b.y; v[6]=b.z; v[7]=b.w;
    } else {
      #pragma unroll
      for (int i = 0; i < 8; ++i) v[i] = 0.0f;
    }
    f16x8 hv, lv;
    #pragma unroll
    for (int i = 0; i < 8; ++i) {
      const _Float16 h = (_Float16)v[i];
      hv[i] = h;
      lv[i] = (_Float16)((v[i] - (float)h) * 4096.0f);
    }
    const size_t off = (size_t)t * 2048 + kb * 128 + col * 8;  // ushort units
    *reinterpret_cast<f16x8*>(tcvt + off)        = hv;
    *reinterpret_cast<f16x8*>(tcvt + off + 1024) = lv;
  }
}

// ---------------- Kernel B (MFMA): distances + per-(query,chunk) bottom-5 ----------------
#define MFMA16(A, B, C) __builtin_amdgcn_mfma_f32_16x16x32_f16((A), (B), (C), 0, 0, 0)

__launch_bounds__(256)
__global__ void knn_mfma_kernel(const float* __restrict__ x,
                                const unsigned short* __restrict__ tcvt,
                                const float* __restrict__ t2c,
                                unsigned* __restrict__ pdu,
                                int*      __restrict__ pi,
                                int tiles, int CHN, unsigned jmask) {
  __shared__ unsigned short sbuf[2][GT * 2048];  // 16 KiB, double-buffered

  const int tid  = threadIdx.x;
  const int lane = tid & 63;
  const int w    = __builtin_amdgcn_readfirstlane(tid >> 6);
  const int ci   = blockIdx.x;                  // target chunk
  const int q0w  = blockIdx.y * QBB + w * 16;   // wave's first query
  const int col  = lane & 15;
  const int kb   = lane >> 4;                   // 0..3
  const unsigned kclear = ~jmask;

  // ---- A fragments: 16 queries x 64 d, f16 hi/lo, in regs all kernel ----
  f16x8 ah[2], al[2];
  #pragma unroll
  for (int c = 0; c < 2; ++c) {
    const float* xp = x + (size_t)(q0w + col) * DD + c * 32 + kb * 8;
    const float4 a = *reinterpret_cast<const float4*>(xp);
    const float4 b = *reinterpret_cast<const float4*>(xp + 4);
    float v[8] = {a.x, a.y, a.z, a.w, b.x, b.y, b.z, b.w};
    #pragma unroll
    for (int i = 0; i < 8; ++i) {
      const _Float16 h = (_Float16)v[i];
      ah[c][i] = h;
      al[c][i] = (_Float16)((v[i] - (float)h) * 4096.0f);
    }
  }

  // per-lane bottom-5 packed keys per C-reg slot (4 queries/lane), ascending
  unsigned k0[4], k1[4], k2[4], k3[4], k4[4];
  #pragma unroll
  for (int r = 0; r < 4; ++r) {
    k0[r]=k1[r]=k2[r]=k3[r]=k4[r] = 0xFFFFFFFFu;
  }

  const int NP = tiles / GT;                    // exact (tiles % GT == 0)

  // running pointers
  const size_t tstep = (size_t)CHN * 2048;      // ushorts per j-step
  const unsigned short* gsrc = tcvt + (size_t)ci * 2048 + tid * 8;
  const float* tp  = t2c + (size_t)ci * tiles * 16 + col;

  // ---- prologue: stage phase 0 + bias ----
  #pragma unroll
  for (int g = 0; g < GT; ++g)
    gload16(gsrc + (size_t)g * tstep, &sbuf[0][g * 2048 + tid * 8]);
  float t2cur[GT], t2nxt[GT];
  #pragma unroll
  for (int g = 0; g < GT; ++g) t2cur[g] = tp[g * 16];
  __syncthreads();

  const unsigned short* gp = gsrc + (size_t)GT * tstep;  // phase p+1 tiles
  const float* tpr = tp + GT * 16;                       // phase p+1 bias
  const int lbase = kb * 128 + col * 8;                  // ushort offset of lane frag

  for (int p = 0; p < NP; ++p) {
    const int bp = p & 1;
    // 1) stage phase p+1
    if (p + 1 < NP) {
      #pragma unroll
      for (int g = 0; g < GT; ++g)
        gload16(gp + (size_t)g * tstep, &sbuf[bp ^ 1][g * 2048 + tid * 8]);
      #pragma unroll
      for (int g = 0; g < GT; ++g) t2nxt[g] = tpr[g * 16];
    }
    // 2) compute phase p (GT uniform tiles, 6 MFMA each)
    #pragma unroll
    for (int g = 0; g < GT; ++g) {
      const unsigned jt = (unsigned)(p * GT + g);        // wave-uniform tile ctr
      const unsigned short* tb = &sbuf[bp][g * 2048];
      const f16x8 bh0 = *reinterpret_cast<const f16x8*>(tb + lbase);
      const f16x8 bh1 = *reinterpret_cast<const f16x8*>(tb + lbase + 512);
      const f16x8 bl0 = *reinterpret_cast<const f16x8*>(tb + lbase + 1024);
      const f16x8 bl1 = *reinterpret_cast<const f16x8*>(tb + lbase + 1536);
      const float hv = t2cur[g];                // pre-scaled -t2/2
      f32x4 acc1 = {hv, hv, hv, hv};
      f32x4 acc2 = {0.f, 0.f, 0.f, 0.f};
      acc1 = MFMA16(ah[0], bh0, acc1);
      acc1 = MFMA16(ah[1], bh1, acc1);
      acc2 = MFMA16(ah[0], bl0, acc2);
      acc2 = MFMA16(ah[1], bl1, acc2);
      acc2 = MFMA16(al[0], bh0, acc2);
      acc2 = MFMA16(al[1], bh1, acc2);
      #pragma unroll
      for (int r = 0; r < 4; ++r) {
        const float v = fmaf(acc2[r], 0x1p-12f, acc1[r]);  // v = dot - t2/2
        const unsigned u = __float_as_uint(v);
        const unsigned m = (unsigned)((int)u >> 31) | 0x80000000u;  // monotone map
        const unsigned key = ((u ^ m) & kclear) | jt;
        ins5_u32(key, k0[r], k1[r], k2[r], k3[r], k4[r]);
      }
    }
    #pragma unroll
    for (int g = 0; g < GT; ++g) t2cur[g] = t2nxt[g];
    gp  += (size_t)GT * tstep;
    tpr += GT * 16;
    __syncthreads();
  }

  // ---- merge within each 16-lane group (cold): (key, exact idx) lex merge ----
  const int ibase = ci * 16 + col;
  const int istep = CHN * 16;
  #pragma unroll
  for (int r = 0; r < 4; ++r) {
    unsigned rd[KNN]; int ri[KNN];
    #pragma unroll
    for (int rr = 0; rr < KNN; ++rr) {
      const int head_i = (int)(k0[r] & jmask) * istep + ibase;
      unsigned md = k0[r]; int mi = head_i;
      #pragma unroll
      for (int k = 1; k < 16; k <<= 1) {
        const unsigned od = __shfl_xor(md, k);
        const int      oi = __shfl_xor(mi, k);
        if (pair_lt_u(od, oi, md, mi)) { md = od; mi = oi; }
      }
      rd[rr] = md; ri[rr] = mi;
      if (k0[r] == md && head_i == mi) {        // consume own head
        k0[r]=k1[r]; k1[r]=k2[r]; k2[r]=k3[r]; k3[r]=k4[r]; k4[r]=0xFFFFFFFFu;
      }
    }
    if (col == 0) {
      const int q = q0w + (lane >> 4) * 4 + r;
      const int pbase = q * (CHN * KNN) + ci * KNN;
      #pragma unroll
      for (int rr = 0; rr < KNN; ++rr) { pdu[pbase + rr] = rd[rr]; pi[pbase + rr] = ri[rr]; }
    }
  }
}

// ------- Kernel C (tier-1): unsigned-key merge of partials, gather, mean -------
__launch_bounds__(64)
__global__ void merge_kernel_u(const float* __restrict__ tg,
                               const unsigned* __restrict__ pdu,
                               const int*      __restrict__ pi,
                               float* __restrict__ out, int chn) {
  const int q    = blockIdx.x;
  const int lane = threadIdx.x;   // 64 threads
  const int M    = chn * KNN;     // up to 320 candidates
  const int pb   = q * M;
  unsigned cd[5]; int cix[5];
  #pragma unroll
  for (int s = 0; s < 5; ++s) {
    const int i = lane + s * 64;
    const bool v = i < M;
    cd[s]  = v ? pdu[pb + i] : 0xFFFFFFFFu;
    cix[s] = v ? pi[pb + i] : 0x7FFFFFFF;
  }
  int sel[KNN];
  #pragma unroll
  for (int r = 0; r < KNN; ++r) {
    unsigned md = cd[0]; int mi = cix[0];
    #pragma unroll
    for (int s = 1; s < 5; ++s)
      if (pair_lt_u(cd[s], cix[s], md, mi)) { md = cd[s]; mi = cix[s]; }
    #pragma unroll
    for (int k = 1; k < 64; k <<= 1) {
      const unsigned od = __shfl_xor(md, k);
      const int      oi = __shfl_xor(mi, k);
      if (pair_lt_u(od, oi, md, mi)) { md = od; mi = oi; }
    }
    sel[r] = mi;
    #pragma unroll
    for (int s = 0; s < 5; ++s)
      if (cd[s] == md && cix[s] == mi) { cd[s] = 0xFFFFFFFFu; cix[s] = 0x7FFFFFFF; }
  }
  float s = 0.0f;
  #pragma unroll
  for (int r = 0; r < KNN; ++r) s += tg[(size_t)sel[r] * DD + lane];
  out[(size_t)q * DD + lane] = s / 5.0f;
}

// ------- Kernel C (tier-2/3): float merge (unchanged) -------
__launch_bounds__(64)
__global__ void merge_kernel_f(const float* __restrict__ tg,
                               const float* __restrict__ pd,
                               const int*   __restrict__ pi,
                               float* __restrict__ out, int chn) {
  const int q    = blockIdx.x;
  const int lane = threadIdx.x;
  const int M    = chn * KNN;
  const int pb   = q * M;
  float cd[5]; int cix[5];
  #pragma unroll
  for (int s = 0; s < 5; ++s) {
    const int i = lane + s * 64;
    const bool v = i < M;
    cd[s]  = v ? pd[pb + i] : -1e30f;
    cix[s] = v ? pi[pb + i] : 0;
  }
  int sel[KNN];
  #pragma unroll
  for (int r = 0; r < KNN; ++r) {
    float md = cd[0]; int mi = cix[0];
    #pragma unroll
    for (int s = 1; s < 5; ++s)
      if (pair_gt(cd[s], cix[s], md, mi)) { md = cd[s]; mi = cix[s]; }
    #pragma unroll
    for (int k = 1; k < 64; k <<= 1) {
      const float od = __shfl_xor(md, k);
      const int   oi = __shfl_xor(mi, k);
      if (pair_gt(od, oi, md, mi)) { md = od; mi = oi; }
    }
    sel[r] = mi;
    #pragma unroll
    for (int s = 0; s < 5; ++s)
      if (cix[s] == mi && cd[s] == md) cd[s] = -1e30f;
  }
  float s = 0.0f;
  #pragma unroll
  for (int r = 0; r < KNN; ++r) s += tg[(size_t)sel[r] * DD + lane];
  out[(size_t)q * DD + lane] = s / 5.0f;
}

// ---------------- Tier-2 (round-3 VALU kernel, fallback if ws too small) ----------------
__launch_bounds__(BLK)
__global__ void knn_partial_kernel(const float* __restrict__ x,
                                   const float* __restrict__ tg,
                                   const float* __restrict__ t2w,
                                   float* __restrict__ pd,
                                   int*   __restrict__ pi,
                                   int N) {
  __shared__ float tbuf[2][KC][NT];

  const int tid  = threadIdx.x;
  const int lane = tid & 63;
  const int w    = __builtin_amdgcn_readfirstlane(tid >> 6);
  const int ci   = blockIdx.x;
  const int q0   = blockIdx.y * QB + w * TQ;
  const float* xq = x + (size_t)q0 * DD;

  float td0[TQ], td1[TQ], td2[TQ], td3[TQ], td4[TQ];
  int   ti0[TQ], ti1[TQ], ti2[TQ], ti3[TQ], ti4[TQ];
  #pragma unroll
  for (int qi = 0; qi < TQ; ++qi) {
    td0[qi]=td1[qi]=td2[qi]=td3[qi]=td4[qi] = -1e30f;
    ti0[qi]=ti1[qi]=ti2[qi]=ti3[qi]=ti4[qi] = 0;
  }

  float acc[TQ][4];
  const int total_tiles = (N + NT - 1) / NT;
  const int mytiles = (ci < total_tiles) ? ((total_tiles - 1 - ci) / CH + 1) : 0;
  const int C = mytiles * 4;

  float4 sva = make_float4(0,0,0,0), svb = make_float4(0,0,0,0);
  const int n0  = tid & 255;
  const int j40 = tid >> 8;
  const int j41 = j40 + 2;
  const float4* tgv = reinterpret_cast<const float4*>(tg);

  if (C > 0) {
    const long r0 = (long)ci * NT + n0;
    if (r0 < N) { sva = tgv[r0 * 16 + j40]; svb = tgv[r0 * 16 + j41]; }
    tbuf[0][j40*4+0][n0] = sva.x;  tbuf[0][j40*4+1][n0] = sva.y;
    tbuf[0][j40*4+2][n0] = sva.z;  tbuf[0][j40*4+3][n0] = sva.w;
    tbuf[0][j41*4+0][n0] = svb.x;  tbuf[0][j41*4+1][n0] = svb.y;
    tbuf[0][j41*4+2][n0] = svb.z;  tbuf[0][j41*4+3][n0] = svb.w;
  }
  __syncthreads();

  for (int c = 0; c < C; ++c) {
    const int b       = c & 1;
    const int kc      = c & 3;
    const int tileidx = ci + (c >> 2) * CH;
    const bool more   = (c + 1 < C);

    if (more) {
      const int gc2   = c + 1;
      const int kc2   = gc2 & 3;
      const int tile2 = ci + (gc2 >> 2) * CH;
      const long r0n  = (long)tile2 * NT + n0;
      sva = make_float4(0,0,0,0);
      svb = make_float4(0,0,0,0);
      if (r0n < N) {
        sva = tgv[r0n * 16 + kc2 * 4 + j40];
        svb = tgv[r0n * 16 + kc2 * 4 + j41];
      }
    }

    if (kc == 0) {
      #pragma unroll
      for (int qi = 0; qi < TQ; ++qi) {
        acc[qi][0]=0.f; acc[qi][1]=0.f; acc[qi][2]=0.f; acc[qi][3]=0.f;
      }
    }
    #pragma unroll
    for (int h = 0; h < 2; ++h) {
      const int dbase = kc * KC + h * 8;
      float qs[TQ][8];
      #pragma unroll
      for (int qi = 0; qi < TQ; ++qi) {
        const float4 qa = *reinterpret_cast<const float4*>(xq + qi * DD + dbase);
        const float4 qb = *reinterpret_cast<const float4*>(xq + qi * DD + dbase + 4);
        qs[qi][0]=qa.x; qs[qi][1]=qa.y; qs[qi][2]=qa.z; qs[qi][3]=qa.w;
        qs[qi][4]=qb.x; qs[qi][5]=qb.y; qs[qi][6]=qb.z; qs[qi][7]=qb.w;
      }
      #pragma unroll
      for (int dd = 0; dd < 8; ++dd) {
        const float4 tv = *reinterpret_cast<const float4*>(&tbuf[b][h*8+dd][lane*4]);
        #pragma unroll
        for (int qi = 0; qi < TQ; ++qi) {
          acc[qi][0] = fmaf(qs[qi][dd], tv.x, acc[qi][0]);
          acc[qi][1] = fmaf(qs[qi][dd], tv.y, acc[qi][1]);
          acc[qi][2] = fmaf(qs[qi][dd], tv.z, acc[qi][2]);
          acc[qi][3] = fmaf(qs[qi][dd], tv.w, acc[qi][3]);
        }
      }
    }

    if (kc == 3) {
      const int nb = tileidx * NT + lane * 4;
      const float4 t2v = *reinterpret_cast<const float4*>(t2w + nb);
      const float t2a[4] = { t2v.x, t2v.y, t2v.z, t2v.w };
      #pragma unroll
      for (int qi = 0; qi < TQ; ++qi) {
        #pragma unroll
        for (int j = 0; j < 4; ++j) {
          const float r2  = fmaf(-2.0f, acc[qi][j], t2a[j]);
          const int   idx = nb + j;
          if (idx < N && pair_gt(r2, idx, td4[qi], ti4[qi]))
            top5_insert(r2, idx,
                        td0[qi], td1[qi], td2[qi], td3[qi], td4[qi],
                        ti0[qi], ti1[qi], ti2[qi], ti3[qi], ti4[qi]);
        }
      }
    }

    if (more) {
      const int bo = (c + 1) & 1;
      tbuf[bo][j40*4+0][n0] = sva.x;  tbuf[bo][j40*4+1][n0] = sva.y;
      tbuf[bo][j40*4+2][n0] = sva.z;  tbuf[bo][j40*4+3][n0] = sva.w;
      tbuf[bo][j41*4+0][n0] = svb.x;  tbuf[bo][j41*4+1][n0] = svb.y;
      tbuf[bo][j41*4+2][n0] = svb.z;  tbuf[bo][j41*4+3][n0] = svb.w;
    }
    __syncthreads();
  }

  #pragma unroll
  for (int qi = 0; qi < TQ; ++qi) {
    float rd[KNN]; int ri[KNN];
    #pragma unroll
    for (int r = 0; r < KNN; ++r) {
      float md = td0[qi]; int mi = ti0[qi];
      #pragma unroll
      for (int k = 1; k < 64; k <<= 1) {
        const float od = __shfl_xor(md, k);
        const int   oi = __shfl_xor(mi, k);
        if (pair_gt(od, oi, md, mi)) { md = od; mi = oi; }
      }
      rd[r] = md; ri[r] = mi;
      if (ti0[qi] == mi && td0[qi] == md) {
        td0[qi]=td1[qi]; ti0[qi]=ti1[qi];
        td1[qi]=td2[qi]; ti1[qi]=ti2[qi];
        td2[qi]=td3[qi]; ti2[qi]=ti3[qi];
        td3[qi]=td4[qi]; ti3[qi]=ti4[qi];
        td4[qi]=-1e30f;  ti4[qi]=0;
      }
    }
    if (lane == 0) {
      const int pbase = (q0 + qi) * (CH * KNN) + ci * KNN;
      #pragma unroll
      for (int r = 0; r < KNN; ++r) { pd[pbase + r] = rd[r]; pi[pbase + r] = ri[r]; }
    }
  }
}

// ---------------- Tier-3 fallback ----------------
__launch_bounds__(256)
__global__ void knn_fallback(const float* __restrict__ x,
                             const float* __restrict__ tg,
                             float* __restrict__ out, int N) {
  const int q   = blockIdx.x;
  const int tid = threadIdx.x;
  __shared__ float qsh[DD];
  __shared__ float smd[KNN][256];
  __shared__ int   smi[KNN][256];
  if (tid < DD) qsh[tid] = x[(size_t)q * DD + tid];
  __syncthreads();
  float qv[DD];
  #pragma unroll
  for (int d = 0; d < DD; ++d) qv[d] = qsh[d];
  float x2 = 0.0f;
  #pragma unroll
  for (int d = 0; d < DD; ++d) x2 = fmaf(qv[d], qv[d], x2);
  float a0=-1e30f,a1=-1e30f,a2=-1e30f,a3=-1e30f,a4=-1e30f;
  int   i0=0,i1=0,i2=0,i3=0,i4=0;
  for (int n = tid; n < N; n += 256) {
    const float4* tr = reinterpret_cast<const float4*>(tg + (size_t)n * DD);
    float dot = 0.0f, tt = 0.0f;
    #pragma unroll
    for (int k = 0; k < 16; ++k) {
      const float4 tv = tr[k];
      dot = fmaf(qv[4*k+0], tv.x, dot); tt = fmaf(tv.x, tv.x, tt);
      dot = fmaf(qv[4*k+1], tv.y, dot); tt = fmaf(tv.y, tv.y, tt);
      dot = fmaf(qv[4*k+2], tv.z, dot); tt = fmaf(tv.z, tv.z, tt);
      dot = fmaf(qv[4*k+3], tv.w, dot); tt = fmaf(tv.w, tv.w, tt);
    }
    const float d2 = fmaf(-2.0f, dot, x2 + tt);
    if (pair_gt(d2, n, a4, i4))
      top5_insert(d2, n, a0,a1,a2,a3,a4, i0,i1,i2,i3,i4);
  }
  smd[0][tid]=a0; smi[0][tid]=i0;  smd[1][tid]=a1; smi[1][tid]=i1;
  smd[2][tid]=a2; smi[2][tid]=i2;  smd[3][tid]=a3; smi[3][tid]=i3;
  smd[4][tid]=a4; smi[4][tid]=i4;
  __syncthreads();
  if (tid < 64) {
    a0=a1=a2=a3=a4=-1e30f; i0=i1=i2=i3=i4=0;
    for (int src = tid; src < 256; src += 64) {
      #pragma unroll
      for (int r = 0; r < KNN; ++r) {
        const float dd2 = smd[r][src]; const int ii = smi[r][src];
        if (pair_gt(dd2, ii, a4, i4))
          top5_insert(dd2, ii, a0,a1,a2,a3,a4, i0,i1,i2,i3,i4);
      }
    }
    int sel[KNN];
    #pragma unroll
    for (int r = 0; r < KNN; ++r) {
      float md = a0; int mi = i0;
      #pragma unroll
      for (int k = 1; k < 64; k <<= 1) {
        const float od = __shfl_xor(md, k);
        const int   oi = __shfl_xor(mi, k);
        if (pair_gt(od, oi, md, mi)) { md = od; mi = oi; }
      }
      sel[r] = mi;
      if (i0 == mi && a0 == md) {
        a0=a1; i0=i1; a1=a2; i1=i2; a2=a3; i2=i3; a3=a4; i3=i4; a4=-1e30f; i4=0;
      }
    }
    float s = 0.0f;
    #pragma unroll
    for (int r = 0; r < KNN; ++r) s += tg[(size_t)sel[r] * DD + tid];
    out[(size_t)q * DD + tid] = s / 5.0f;
  }
}

extern "C" void kernel_launch(void* const* d_in, const int* in_sizes, int n_in,
                              void* d_out, int out_size, void* d_ws, size_t ws_size,
                              hipStream_t stream) {
  const float* x  = (const float*)d_in[0];
  const float* tg = (const float*)d_in[1];
  float* out = (float*)d_out;
  const int B = in_sizes[0] / DD;   // 2048
  const int N = in_sizes[1] / DD;   // 50000

  // tier-1: Npad multiple of CHN*GT*16 for fully uniform loops
  auto t1_need = [&](int chn, int& npad, int& tt, int& tiles) {
    const int align = chn * GT * NTT;
    npad  = ((N + align - 1) / align) * align;
    tt    = npad / NTT;
    tiles = tt / chn;
    return (size_t)npad * 4 + (size_t)B * chn * KNN * 8 + (size_t)tt * 4096;
  };
  int Npad64, TT64, tiles64, Npad32, TT32, tiles32;
  const size_t need64 = t1_need(64, Npad64, TT64, tiles64);
  const size_t need32 = t1_need(32, Npad32, TT32, tiles32);

  int CHN = 0, Npad = 0, TT = 0, tiles = 0, chnlog = 0;
  unsigned jmask = 63;
  if (ws_size >= need64)      { CHN = 64; Npad = Npad64; TT = TT64; tiles = tiles64; chnlog = 6; jmask = 63;  }
  else if (ws_size >= need32) { CHN = 32; Npad = Npad32; TT = TT32; tiles = tiles32; chnlog = 5; jmask = 127; }

  if (CHN > 0 && (B % QBB) == 0 && tiles <= (int)jmask + 1) {
    const size_t np1 = (size_t)B * CHN * KNN;
    float*          t2c  = (float*)d_ws;
    unsigned*       pdu  = (unsigned*)(t2c + Npad);
    int*            pi   = (int*)(pdu + np1);
    unsigned short* tcvt = (unsigned short*)(pi + np1);
    sqnorm_chunked<<<dim3(Npad / 16), dim3(256), 0, stream>>>(tg, t2c, N, Npad, tiles, chnlog);
    cvt_kernel<<<dim3((TT + 3) / 4), dim3(256), 0, stream>>>(tg, tcvt, N, TT);
    knn_mfma_kernel<<<dim3(CHN, B / QBB), dim3(256), 0, stream>>>(x, tcvt, t2c, pdu, pi, tiles, CHN, jmask);
    merge_kernel_u<<<dim3(B), dim3(64), 0, stream>>>(tg, pdu, pi, out, CHN);
    return;
  }

  // tier-2
  const int    Npad_v    = (N + NT - 1) & ~(NT - 1);
  const size_t np2       = (size_t)B * CH * KNN;
  const size_t need_valu = ((size_t)Npad_v + 2 * np2) * 4;
  if (ws_size >= need_valu && (B % QB) == 0) {
    float* t2 = (float*)d_ws;
    float* pd = t2 + Npad_v;
    int*   pi = (int*)(pd + np2);
    sqnorm_kernel<<<dim3(Npad_v / 16), dim3(256), 0, stream>>>(tg, t2, N, Npad_v);
    knn_partial_kernel<<<dim3(CH, B / QB), dim3(BLK), 0, stream>>>(x, tg, t2, pd, pi, N);
    merge_kernel_f<<<dim3(B), dim3(64), 0, stream>>>(tg, pd, pi, out, CH);
  } else {
    knn_fallback<<<dim3(B), dim3(256), 0, stream>>>(x, tg, out, N);
  }
}

// Round 11
// 98.690 us; speedup vs baseline: 2.7444x; 1.0134x over previous
//
#include <hip/hip_runtime.h>

// KNN (k=5, LARGEST distances per faithful-to-source quirk) + gather-mean.
// x: [B=2048, 64] f32, target: [N=50000, 64] f32, out: [B, 64] f32.
//
// Tier-1 (MFMA): distance GEMM via f16 hi/lo split:
//   x = hi + lo*2^-12 (lo pre-scaled by 2^12, f16-normal)
//   dot ~= hh + 2^-12*(hl + lh)
// Selection key: v = dot - t2/2 (min == farthest), monotone-mapped to u32 with
// the wave-uniform tile counter j embedded in the cleared low mantissa bits.
// Top-5 = 9-op v_min_u32/v_max_u32 insertion network (no compares, no idx regs)
// — round-10's decisive lever (257us -> 100us, super-proportional: the old
// cndmask+idx cascade was a dependency chain).
// Round-11: amortize fixed costs. 512-thr blocks (8 waves, QBB=128) + GT=4:
// phases 25 -> 13 (half the barrier+vmcnt drains), staging amortized 2x,
// 32KB LDS x 4 blocks/CU keeps 32 waves/CU. sqnorm fused into cvt (one fewer
// pass over the 12.8MB target array). Hot insert loop untouched.

typedef _Float16 f16x8 __attribute__((ext_vector_type(8)));
typedef float    f32x4 __attribute__((ext_vector_type(4)));

constexpr int KNN = 5;
constexpr int DD  = 64;    // feature dim
constexpr int NTT = 16;    // targets per MFMA tile
constexpr int GT  = 4;     // tiles per phase (32KB LDS dbuf)
constexpr int QBB = 128;   // queries per block (8 waves x 16)

// tier-2 (VALU) constants — round-3 kernel kept as fallback
constexpr int TQ  = 4;
constexpr int QB  = 32;
constexpr int NT  = 256;
constexpr int KC  = 16;
constexpr int CH  = 16;
constexpr int BLK = 512;

__device__ __forceinline__ bool pair_gt(float ad, int ai, float bd, int bi) {
  return (ad > bd) || (ad == bd && ai < bi);
}
__device__ __forceinline__ bool pair_lt_u(unsigned ad, int ai, unsigned bd, int bi) {
  return (ad < bd) || (ad == bd && ai < bi);
}

// max-semantics sorted insert (tier-2/3 paths)
__device__ __forceinline__ void top5_insert(float d2, int idx,
    float& t0d, float& t1d, float& t2d, float& t3d, float& t4d,
    int&   t0i, int&   t1i, int&   t2i, int&   t3i, int&   t4i) {
  const bool b3 = pair_gt(d2, idx, t3d, t3i);
  const bool b2 = pair_gt(d2, idx, t2d, t2i);
  const bool b1 = pair_gt(d2, idx, t1d, t1i);
  const bool b0 = pair_gt(d2, idx, t0d, t0i);
  t4d = b3 ? t3d : d2;               t4i = b3 ? t3i : idx;
  t3d = b3 ? (b2 ? t2d : d2) : t3d;  t3i = b3 ? (b2 ? t2i : idx) : t3i;
  t2d = b2 ? (b1 ? t1d : d2) : t2d;  t2i = b2 ? (b1 ? t1i : idx) : t2i;
  t1d = b1 ? (b0 ? t0d : d2) : t1d;  t1i = b1 ? (b0 ? t0i : idx) : t1i;
  t0d = b0 ? d2 : t0d;               t0i = b0 ? idx : t0i;
}

// 9-op min/max insertion into ascending sorted 5 (tier-1 hot path, u32 keys)
__device__ __forceinline__ void ins5_u32(unsigned c,
    unsigned& a0, unsigned& a1, unsigned& a2, unsigned& a3, unsigned& a4) {
  unsigned t;
  t = min(a0, c); c = max(a0, c); a0 = t;
  t = min(a1, c); c = max(a1, c); a1 = t;
  t = min(a2, c); c = max(a2, c); a2 = t;
  t = min(a3, c); c = max(a3, c); a3 = t;
  a4 = min(a4, c);
}

__device__ __forceinline__ void gload16(const void* g, void* l) {
  __builtin_amdgcn_global_load_lds(
      (const __attribute__((address_space(1))) unsigned int*)g,
      (__attribute__((address_space(3))) unsigned int*)l, 16, 0, 0);
}

// ------- Kernel A (tier-1, fused): f16 hi/lo tile image + bias image -------
// tcvt per tile (4096B): [term(2)][kb(8)][col(16)][i(8)] f16; k = kb*8+i.
// t2c[ci][j][col] = -||t||^2/2 (pad rows +1e30), chunk-contiguous.
__launch_bounds__(256)
__global__ void prep_kernel(const float* __restrict__ tg,
                            unsigned short* __restrict__ tcvt,
                            float* __restrict__ t2c,
                            int N, int TT, int tiles, int chnlog) {
  const int tid  = threadIdx.x;
  const int lane = tid & 63;
  const int w    = __builtin_amdgcn_readfirstlane(tid >> 6);
  const int t    = blockIdx.x * 4 + w;          // tile index
  if (t >= TT) return;
  const int col   = lane & 15;
  const int khalf = lane >> 4;                  // 0..3
  const int row   = t * NTT + col;              // global target row
  float ss = 0.0f;
  #pragma unroll
  for (int j = 0; j < 2; ++j) {
    const int kb = khalf * 2 + j;               // 0..7
    float v[8];
    if (row < N) {
      const float4 a = *reinterpret_cast<const float4*>(tg + (size_t)row * DD + kb * 8);
      const float4 b = *reinterpret_cast<const float4*>(tg + (size_t)row * DD + kb * 8 + 4);
      v[0]=a.x; v[1]=a.y; v[2]=a.z; v[3]=a.w;
      v[4]=b.x; v[5]=b.y; v[6]=b.z; v[7]=b.w;
    } else {
      #pragma unroll
      for (int i = 0; i < 8; ++i) v[i] = 0.0f;
    }
    f16x8 hv, lv;
    #pragma unroll
    for (int i = 0; i < 8; ++i) {
      const _Float16 h = (_Float16)v[i];
      hv[i] = h;
      lv[i] = (_Float16)((v[i] - (float)h) * 4096.0f);
      ss = fmaf(v[i], v[i], ss);
    }
    const size_t off = (size_t)t * 2048 + kb * 128 + col * 8;  // ushort units
    *reinterpret_cast<f16x8*>(tcvt + off)        = hv;
    *reinterpret_cast<f16x8*>(tcvt + off + 1024) = lv;
  }
  // row-norm: reduce across the 4 lanes sharing this col (lane bits 4,5)
  ss += __shfl_xor(ss, 16);
  ss += __shfl_xor(ss, 32);
  if (khalf == 0) {
    const float bias = (row < N) ? -0.5f * ss : 1e30f;
    const int ci = t & ((1 << chnlog) - 1);
    const int jj = t >> chnlog;
    t2c[((size_t)ci * tiles + jj) * 16 + col] = bias;
  }
}

// ------- Kernel A (tier-2): linear sqnorm (pad rows -1e30) -------
__launch_bounds__(256)
__global__ void sqnorm_kernel(const float* __restrict__ tg,
                              float* __restrict__ t2, int N, int Npad) {
  const int tid  = threadIdx.x;
  const int lane = tid & 63;
  const int wv   = tid >> 6;
  const int row  = blockIdx.x * 16 + wv * 4 + (lane >> 4);
  const int f4   = lane & 15;
  if (row >= Npad) return;
  float s = -1e30f;
  if (row < N) {
    const float4 v = reinterpret_cast<const float4*>(tg)[(size_t)row * 16 + f4];
    s = v.x*v.x + v.y*v.y + v.z*v.z + v.w*v.w;
    s += __shfl_xor(s, 1);
    s += __shfl_xor(s, 2);
    s += __shfl_xor(s, 4);
    s += __shfl_xor(s, 8);
  }
  if (f4 == 0) t2[row] = s;
}

// ---------------- Kernel B (MFMA): distances + per-(query,chunk) bottom-5 ----------------
#define MFMA16(A, B, C) __builtin_amdgcn_mfma_f32_16x16x32_f16((A), (B), (C), 0, 0, 0)

__launch_bounds__(512)
__global__ void knn_mfma_kernel(const float* __restrict__ x,
                                const unsigned short* __restrict__ tcvt,
                                const float* __restrict__ t2c,
                                unsigned* __restrict__ pdu,
                                int*      __restrict__ pi,
                                int tiles, int CHN, unsigned jmask) {
  __shared__ unsigned short sbuf[2][GT * 2048];  // 32 KiB, double-buffered

  const int tid  = threadIdx.x;
  const int lane = tid & 63;
  const int w    = __builtin_amdgcn_readfirstlane(tid >> 6);  // 0..7
  const int ci   = blockIdx.x;                  // target chunk
  const int q0w  = blockIdx.y * QBB + w * 16;   // wave's first query
  const int col  = lane & 15;
  const int kb   = lane >> 4;                   // 0..3
  const unsigned kclear = ~jmask;
  const int soff = (tid & 255) * 8;             // staging offset in a tile (ushorts)
  const int sg   = tid >> 8;                    // 0..1: stages tiles {sg, sg+2}

  // ---- A fragments: 16 queries x 64 d, f16 hi/lo, in regs all kernel ----
  f16x8 ah[2], al[2];
  #pragma unroll
  for (int c = 0; c < 2; ++c) {
    const float* xp = x + (size_t)(q0w + col) * DD + c * 32 + kb * 8;
    const float4 a = *reinterpret_cast<const float4*>(xp);
    const float4 b = *reinterpret_cast<const float4*>(xp + 4);
    float v[8] = {a.x, a.y, a.z, a.w, b.x, b.y, b.z, b.w};
    #pragma unroll
    for (int i = 0; i < 8; ++i) {
      const _Float16 h = (_Float16)v[i];
      ah[c][i] = h;
      al[c][i] = (_Float16)((v[i] - (float)h) * 4096.0f);
    }
  }

  // per-lane bottom-5 packed keys per C-reg slot (4 queries/lane), ascending
  unsigned k0[4], k1[4], k2[4], k3[4], k4[4];
  #pragma unroll
  for (int r = 0; r < 4; ++r) {
    k0[r]=k1[r]=k2[r]=k3[r]=k4[r] = 0xFFFFFFFFu;
  }

  const int NP = tiles / GT;                    // exact (tiles % GT == 0)

  // running pointers
  const size_t tstep = (size_t)CHN * 2048;      // ushorts per j-step
  const unsigned short* gsrc = tcvt + (size_t)ci * 2048 + soff;
  const float* tp  = t2c + (size_t)ci * tiles * 16 + col;

  // ---- prologue: stage phase 0 + bias ----
  #pragma unroll
  for (int s = 0; s < 2; ++s) {
    const int g = sg + s * 2;
    gload16(gsrc + (size_t)g * tstep, &sbuf[0][g * 2048 + soff]);
  }
  float t2cur[GT], t2nxt[GT];
  #pragma unroll
  for (int g = 0; g < GT; ++g) t2cur[g] = tp[g * 16];
  __syncthreads();

  const unsigned short* gp = gsrc + (size_t)GT * tstep;  // phase p+1 tiles
  const float* tpr = tp + GT * 16;                       // phase p+1 bias
  const int lbase = kb * 128 + col * 8;                  // ushort offset of lane frag

  for (int p = 0; p < NP; ++p) {
    const int bp = p & 1;
    // 1) stage phase p+1
    if (p + 1 < NP) {
      #pragma unroll
      for (int s = 0; s < 2; ++s) {
        const int g = sg + s * 2;
        gload16(gp + (size_t)g * tstep, &sbuf[bp ^ 1][g * 2048 + soff]);
      }
      #pragma unroll
      for (int g = 0; g < GT; ++g) t2nxt[g] = tpr[g * 16];
    }
    // 2) compute phase p (GT uniform tiles, 6 MFMA each)
    #pragma unroll
    for (int g = 0; g < GT; ++g) {
      const unsigned jt = (unsigned)(p * GT + g);        // wave-uniform tile ctr
      const unsigned short* tb = &sbuf[bp][g * 2048];
      const f16x8 bh0 = *reinterpret_cast<const f16x8*>(tb + lbase);
      const f16x8 bh1 = *reinterpret_cast<const f16x8*>(tb + lbase + 512);
      const f16x8 bl0 = *reinterpret_cast<const f16x8*>(tb + lbase + 1024);
      const f16x8 bl1 = *reinterpret_cast<const f16x8*>(tb + lbase + 1536);
      const float hv = t2cur[g];                // pre-scaled -t2/2
      f32x4 acc1 = {hv, hv, hv, hv};
      f32x4 acc2 = {0.f, 0.f, 0.f, 0.f};
      acc1 = MFMA16(ah[0], bh0, acc1);
      acc1 = MFMA16(ah[1], bh1, acc1);
      acc2 = MFMA16(ah[0], bl0, acc2);
      acc2 = MFMA16(ah[1], bl1, acc2);
      acc2 = MFMA16(al[0], bh0, acc2);
      acc2 = MFMA16(al[1], bh1, acc2);
      #pragma unroll
      for (int r = 0; r < 4; ++r) {
        const float v = fmaf(acc2[r], 0x1p-12f, acc1[r]);  // v = dot - t2/2
        const unsigned u = __float_as_uint(v);
        const unsigned m = (unsigned)((int)u >> 31) | 0x80000000u;  // monotone map
        const unsigned key = ((u ^ m) & kclear) | jt;
        ins5_u32(key, k0[r], k1[r], k2[r], k3[r], k4[r]);
      }
    }
    #pragma unroll
    for (int g = 0; g < GT; ++g) t2cur[g] = t2nxt[g];
    gp  += (size_t)GT * tstep;
    tpr += GT * 16;
    __syncthreads();
  }

  // ---- merge within each 16-lane group (cold): (key, exact idx) lex merge ----
  const int ibase = ci * 16 + col;
  const int istep = CHN * 16;
  #pragma unroll
  for (int r = 0; r < 4; ++r) {
    unsigned rd[KNN]; int ri[KNN];
    #pragma unroll
    for (int rr = 0; rr < KNN; ++rr) {
      const int head_i = (int)(k0[r] & jmask) * istep + ibase;
      unsigned md = k0[r]; int mi = head_i;
      #pragma unroll
      for (int k = 1; k < 16; k <<= 1) {
        const unsigned od = __shfl_xor(md, k);
        const int      oi = __shfl_xor(mi, k);
        if (pair_lt_u(od, oi, md, mi)) { md = od; mi = oi; }
      }
      rd[rr] = md; ri[rr] = mi;
      if (k0[r] == md && head_i == mi) {        // consume own head
        k0[r]=k1[r]; k1[r]=k2[r]; k2[r]=k3[r]; k3[r]=k4[r]; k4[r]=0xFFFFFFFFu;
      }
    }
    if (col == 0) {
      const int q = q0w + (lane >> 4) * 4 + r;
      const int pbase = q * (CHN * KNN) + ci * KNN;
      #pragma unroll
      for (int rr = 0; rr < KNN; ++rr) { pdu[pbase + rr] = rd[rr]; pi[pbase + rr] = ri[rr]; }
    }
  }
}

// ------- Kernel C (tier-1): unsigned-key merge of partials, gather, mean -------
__launch_bounds__(64)
__global__ void merge_kernel_u(const float* __restrict__ tg,
                               const unsigned* __restrict__ pdu,
                               const int*      __restrict__ pi,
                               float* __restrict__ out, int chn) {
  const int q    = blockIdx.x;
  const int lane = threadIdx.x;   // 64 threads
  const int M    = chn * KNN;     // up to 320 candidates
  const int pb   = q * M;
  unsigned cd[5]; int cix[5];
  #pragma unroll
  for (int s = 0; s < 5; ++s) {
    const int i = lane + s * 64;
    const bool v = i < M;
    cd[s]  = v ? pdu[pb + i] : 0xFFFFFFFFu;
    cix[s] = v ? pi[pb + i] : 0x7FFFFFFF;
  }
  int sel[KNN];
  #pragma unroll
  for (int r = 0; r < KNN; ++r) {
    unsigned md = cd[0]; int mi = cix[0];
    #pragma unroll
    for (int s = 1; s < 5; ++s)
      if (pair_lt_u(cd[s], cix[s], md, mi)) { md = cd[s]; mi = cix[s]; }
    #pragma unroll
    for (int k = 1; k < 64; k <<= 1) {
      const unsigned od = __shfl_xor(md, k);
      const int      oi = __shfl_xor(mi, k);
      if (pair_lt_u(od, oi, md, mi)) { md = od; mi = oi; }
    }
    sel[r] = mi;
    #pragma unroll
    for (int s = 0; s < 5; ++s)
      if (cd[s] == md && cix[s] == mi) { cd[s] = 0xFFFFFFFFu; cix[s] = 0x7FFFFFFF; }
  }
  float s = 0.0f;
  #pragma unroll
  for (int r = 0; r < KNN; ++r) s += tg[(size_t)sel[r] * DD + lane];
  out[(size_t)q * DD + lane] = s / 5.0f;
}

// ------- Kernel C (tier-2/3): float merge (unchanged) -------
__launch_bounds__(64)
__global__ void merge_kernel_f(const float* __restrict__ tg,
                               const float* __restrict__ pd,
                               const int*   __restrict__ pi,
                               float* __restrict__ out, int chn) {
  const int q    = blockIdx.x;
  const int lane = threadIdx.x;
  const int M    = chn * KNN;
  const int pb   = q * M;
  float cd[5]; int cix[5];
  #pragma unroll
  for (int s = 0; s < 5; ++s) {
    const int i = lane + s * 64;
    const bool v = i < M;
    cd[s]  = v ? pd[pb + i] : -1e30f;
    cix[s] = v ? pi[pb + i] : 0;
  }
  int sel[KNN];
  #pragma unroll
  for (int r = 0; r < KNN; ++r) {
    float md = cd[0]; int mi = cix[0];
    #pragma unroll
    for (int s = 1; s < 5; ++s)
      if (pair_gt(cd[s], cix[s], md, mi)) { md = cd[s]; mi = cix[s]; }
    #pragma unroll
    for (int k = 1; k < 64; k <<= 1) {
      const float od = __shfl_xor(md, k);
      const int   oi = __shfl_xor(mi, k);
      if (pair_gt(od, oi, md, mi)) { md = od; mi = oi; }
    }
    sel[r] = mi;
    #pragma unroll
    for (int s = 0; s < 5; ++s)
      if (cix[s] == mi && cd[s] == md) cd[s] = -1e30f;
  }
  float s = 0.0f;
  #pragma unroll
  for (int r = 0; r < KNN; ++r) s += tg[(size_t)sel[r] * DD + lane];
  out[(size_t)q * DD + lane] = s / 5.0f;
}

// ---------------- Tier-2 (round-3 VALU kernel, fallback if ws too small) ----------------
__launch_bounds__(BLK)
__global__ void knn_partial_kernel(const float* __restrict__ x,
                                   const float* __restrict__ tg,
                                   const float* __restrict__ t2w,
                                   float* __restrict__ pd,
                                   int*   __restrict__ pi,
                                   int N) {
  __shared__ float tbuf[2][KC][NT];

  const int tid  = threadIdx.x;
  const int lane = tid & 63;
  const int w    = __builtin_amdgcn_readfirstlane(tid >> 6);
  const int ci   = blockIdx.x;
  const int q0   = blockIdx.y * QB + w * TQ;
  const float* xq = x + (size_t)q0 * DD;

  float td0[TQ], td1[TQ], td2[TQ], td3[TQ], td4[TQ];
  int   ti0[TQ], ti1[TQ], ti2[TQ], ti3[TQ], ti4[TQ];
  #pragma unroll
  for (int qi = 0; qi < TQ; ++qi) {
    td0[qi]=td1[qi]=td2[qi]=td3[qi]=td4[qi] = -1e30f;
    ti0[qi]=ti1[qi]=ti2[qi]=ti3[qi]=ti4[qi] = 0;
  }

  float acc[TQ][4];
  const int total_tiles = (N + NT - 1) / NT;
  const int mytiles = (ci < total_tiles) ? ((total_tiles - 1 - ci) / CH + 1) : 0;
  const int C = mytiles * 4;

  float4 sva = make_float4(0,0,0,0), svb = make_float4(0,0,0,0);
  const int n0  = tid & 255;
  const int j40 = tid >> 8;
  const int j41 = j40 + 2;
  const float4* tgv = reinterpret_cast<const float4*>(tg);

  if (C > 0) {
    const long r0 = (long)ci * NT + n0;
    if (r0 < N) { sva = tgv[r0 * 16 + j40]; svb = tgv[r0 * 16 + j41]; }
    tbuf[0][j40*4+0][n0] = sva.x;  tbuf[0][j40*4+1][n0] = sva.y;
    tbuf[0][j40*4+2][n0] = sva.z;  tbuf[0][j40*4+3][n0] = sva.w;
    tbuf[0][j41*4+0][n0] = svb.x;  tbuf[0][j41*4+1][n0] = svb.y;
    tbuf[0][j41*4+2][n0] = svb.z;  tbuf[0][j41*4+3][n0] = svb.w;
  }
  __syncthreads();

  for (int c = 0; c < C; ++c) {
    const int b       = c & 1;
    const int kc      = c & 3;
    const int tileidx = ci + (c >> 2) * CH;
    const bool more   = (c + 1 < C);

    if (more) {
      const int gc2   = c + 1;
      const int kc2   = gc2 & 3;
      const int tile2 = ci + (gc2 >> 2) * CH;
      const long r0n  = (long)tile2 * NT + n0;
      sva = make_float4(0,0,0,0);
      svb = make_float4(0,0,0,0);
      if (r0n < N) {
        sva = tgv[r0n * 16 + kc2 * 4 + j40];
        svb = tgv[r0n * 16 + kc2 * 4 + j41];
      }
    }

    if (kc == 0) {
      #pragma unroll
      for (int qi = 0; qi < TQ; ++qi) {
        acc[qi][0]=0.f; acc[qi][1]=0.f; acc[qi][2]=0.f; acc[qi][3]=0.f;
      }
    }
    #pragma unroll
    for (int h = 0; h < 2; ++h) {
      const int dbase = kc * KC + h * 8;
      float qs[TQ][8];
      #pragma unroll
      for (int qi = 0; qi < TQ; ++qi) {
        const float4 qa = *reinterpret_cast<const float4*>(xq + qi * DD + dbase);
        const float4 qb = *reinterpret_cast<const float4*>(xq + qi * DD + dbase + 4);
        qs[qi][0]=qa.x; qs[qi][1]=qa.y; qs[qi][2]=qa.z; qs[qi][3]=qa.w;
        qs[qi][4]=qb.x; qs[qi][5]=qb.y; qs[qi][6]=qb.z; qs[qi][7]=qb.w;
      }
      #pragma unroll
      for (int dd = 0; dd < 8; ++dd) {
        const float4 tv = *reinterpret_cast<const float4*>(&tbuf[b][h*8+dd][lane*4]);
        #pragma unroll
        for (int qi = 0; qi < TQ; ++qi) {
          acc[qi][0] = fmaf(qs[qi][dd], tv.x, acc[qi][0]);
          acc[qi][1] = fmaf(qs[qi][dd], tv.y, acc[qi][1]);
          acc[qi][2] = fmaf(qs[qi][dd], tv.z, acc[qi][2]);
          acc[qi][3] = fmaf(qs[qi][dd], tv.w, acc[qi][3]);
        }
      }
    }

    if (kc == 3) {
      const int nb = tileidx * NT + lane * 4;
      const float4 t2v = *reinterpret_cast<const float4*>(t2w + nb);
      const float t2a[4] = { t2v.x, t2v.y, t2v.z, t2v.w };
      #pragma unroll
      for (int qi = 0; qi < TQ; ++qi) {
        #pragma unroll
        for (int j = 0; j < 4; ++j) {
          const float r2  = fmaf(-2.0f, acc[qi][j], t2a[j]);
          const int   idx = nb + j;
          if (idx < N && pair_gt(r2, idx, td4[qi], ti4[qi]))
            top5_insert(r2, idx,
                        td0[qi], td1[qi], td2[qi], td3[qi], td4[qi],
                        ti0[qi], ti1[qi], ti2[qi], ti3[qi], ti4[qi]);
        }
      }
    }

    if (more) {
      const int bo = (c + 1) & 1;
      tbuf[bo][j40*4+0][n0] = sva.x;  tbuf[bo][j40*4+1][n0] = sva.y;
      tbuf[bo][j40*4+2][n0] = sva.z;  tbuf[bo][j40*4+3][n0] = sva.w;
      tbuf[bo][j41*4+0][n0] = svb.x;  tbuf[bo][j41*4+1][n0] = svb.y;
      tbuf[bo][j41*4+2][n0] = svb.z;  tbuf[bo][j41*4+3][n0] = svb.w;
    }
    __syncthreads();
  }

  #pragma unroll
  for (int qi = 0; qi < TQ; ++qi) {
    float rd[KNN]; int ri[KNN];
    #pragma unroll
    for (int r = 0; r < KNN; ++r) {
      float md = td0[qi]; int mi = ti0[qi];
      #pragma unroll
      for (int k = 1; k < 64; k <<= 1) {
        const float od = __shfl_xor(md, k);
        const int   oi = __shfl_xor(mi, k);
        if (pair_gt(od, oi, md, mi)) { md = od; mi = oi; }
      }
      rd[r] = md; ri[r] = mi;
      if (ti0[qi] == mi && td0[qi] == md) {
        td0[qi]=td1[qi]; ti0[qi]=ti1[qi];
        td1[qi]=td2[qi]; ti1[qi]=ti2[qi];
        td2[qi]=td3[qi]; ti2[qi]=ti3[qi];
        td3[qi]=td4[qi]; ti3[qi]=ti4[qi];
        td4[qi]=-1e30f;  ti4[qi]=0;
      }
    }
    if (lane == 0) {
      const int pbase = (q0 + qi) * (CH * KNN) + ci * KNN;
      #pragma unroll
      for (int r = 0; r < KNN; ++r) { pd[pbase + r] = rd[r]; pi[pbase + r] = ri[r]; }
    }
  }
}

// ---------------- Tier-3 fallback ----------------
__launch_bounds__(256)
__global__ void knn_fallback(const float* __restrict__ x,
                             const float* __restrict__ tg,
                             float* __restrict__ out, int N) {
  const int q   = blockIdx.x;
  const int tid = threadIdx.x;
  __shared__ float qsh[DD];
  __shared__ float smd[KNN][256];
  __shared__ int   smi[KNN][256];
  if (tid < DD) qsh[tid] = x[(size_t)q * DD + tid];
  __syncthreads();
  float qv[DD];
  #pragma unroll
  for (int d = 0; d < DD; ++d) qv[d] = qsh[d];
  float x2 = 0.0f;
  #pragma unroll
  for (int d = 0; d < DD; ++d) x2 = fmaf(qv[d], qv[d], x2);
  float a0=-1e30f,a1=-1e30f,a2=-1e30f,a3=-1e30f,a4=-1e30f;
  int   i0=0,i1=0,i2=0,i3=0,i4=0;
  for (int n = tid; n < N; n += 256) {
    const float4* tr = reinterpret_cast<const float4*>(tg + (size_t)n * DD);
    float dot = 0.0f, tt = 0.0f;
    #pragma unroll
    for (int k = 0; k < 16; ++k) {
      const float4 tv = tr[k];
      dot = fmaf(qv[4*k+0], tv.x, dot); tt = fmaf(tv.x, tv.x, tt);
      dot = fmaf(qv[4*k+1], tv.y, dot); tt = fmaf(tv.y, tv.y, tt);
      dot = fmaf(qv[4*k+2], tv.z, dot); tt = fmaf(tv.z, tv.z, tt);
      dot = fmaf(qv[4*k+3], tv.w, dot); tt = fmaf(tv.w, tv.w, tt);
    }
    const float d2 = fmaf(-2.0f, dot, x2 + tt);
    if (pair_gt(d2, n, a4, i4))
      top5_insert(d2, n, a0,a1,a2,a3,a4, i0,i1,i2,i3,i4);
  }
  smd[0][tid]=a0; smi[0][tid]=i0;  smd[1][tid]=a1; smi[1][tid]=i1;
  smd[2][tid]=a2; smi[2][tid]=i2;  smd[3][tid]=a3; smi[3][tid]=i3;
  smd[4][tid]=a4; smi[4][tid]=i4;
  __syncthreads();
  if (tid < 64) {
    a0=a1=a2=a3=a4=-1e30f; i0=i1=i2=i3=i4=0;
    for (int src = tid; src < 256; src += 64) {
      #pragma unroll
      for (int r = 0; r < KNN; ++r) {
        const float dd2 = smd[r][src]; const int ii = smi[r][src];
        if (pair_gt(dd2, ii, a4, i4))
          top5_insert(dd2, ii, a0,a1,a2,a3,a4, i0,i1,i2,i3,i4);
      }
    }
    int sel[KNN];
    #pragma unroll
    for (int r = 0; r < KNN; ++r) {
      float md = a0; int mi = i0;
      #pragma unroll
      for (int k = 1; k < 64; k <<= 1) {
        const float od = __shfl_xor(md, k);
        const int   oi = __shfl_xor(mi, k);
        if (pair_gt(od, oi, md, mi)) { md = od; mi = oi; }
      }
      sel[r] = mi;
      if (i0 == mi && a0 == md) {
        a0=a1; i0=i1; a1=a2; i1=i2; a2=a3; i2=i3; a3=a4; i3=i4; a4=-1e30f; i4=0;
      }
    }
    float s = 0.0f;
    #pragma unroll
    for (int r = 0; r < KNN; ++r) s += tg[(size_t)sel[r] * DD + tid];
    out[(size_t)q * DD + tid] = s / 5.0f;
  }
}

extern "C" void kernel_launch(void* const* d_in, const int* in_sizes, int n_in,
                              void* d_out, int out_size, void* d_ws, size_t ws_size,
                              hipStream_t stream) {
  const float* x  = (const float*)d_in[0];
  const float* tg = (const float*)d_in[1];
  float* out = (float*)d_out;
  const int B = in_sizes[0] / DD;   // 2048
  const int N = in_sizes[1] / DD;   // 50000

  // tier-1: Npad multiple of CHN*GT*16 for fully uniform loops
  auto t1_need = [&](int chn, int& npad, int& tt, int& tiles) {
    const int align = chn * GT * NTT;
    npad  = ((N + align - 1) / align) * align;
    tt    = npad / NTT;
    tiles = tt / chn;
    return (size_t)npad * 4 + (size_t)B * chn * KNN * 8 + (size_t)tt * 4096;
  };
  int Npad64, TT64, tiles64, Npad32, TT32, tiles32;
  const size_t need64 = t1_need(64, Npad64, TT64, tiles64);
  const size_t need32 = t1_need(32, Npad32, TT32, tiles32);

  int CHN = 0, Npad = 0, TT = 0, tiles = 0, chnlog = 0;
  unsigned jmask = 63;
  if (ws_size >= need64)      { CHN = 64; Npad = Npad64; TT = TT64; tiles = tiles64; chnlog = 6; jmask = 63;  }
  else if (ws_size >= need32) { CHN = 32; Npad = Npad32; TT = TT32; tiles = tiles32; chnlog = 5; jmask = 127; }

  if (CHN > 0 && (B % QBB) == 0 && tiles <= (int)jmask + 1) {
    const size_t np1 = (size_t)B * CHN * KNN;
    float*          t2c  = (float*)d_ws;
    unsigned*       pdu  = (unsigned*)(t2c + Npad);
    int*            pi   = (int*)(pdu + np1);
    unsigned short* tcvt = (unsigned short*)(pi + np1);
    prep_kernel<<<dim3((TT + 3) / 4), dim3(256), 0, stream>>>(tg, tcvt, t2c, N, TT, tiles, chnlog);
    knn_mfma_kernel<<<dim3(CHN, B / QBB), dim3(512), 0, stream>>>(x, tcvt, t2c, pdu, pi, tiles, CHN, jmask);
    merge_kernel_u<<<dim3(B), dim3(64), 0, stream>>>(tg, pdu, pi, out, CHN);
    return;
  }

  // tier-2
  const int    Npad_v    = (N + NT - 1) & ~(NT - 1);
  const size_t np2       = (size_t)B * CH * KNN;
  const size_t need_valu = ((size_t)Npad_v + 2 * np2) * 4;
  if (ws_size >= need_valu && (B % QB) == 0) {
    float* t2 = (float*)d_ws;
    float* pd = t2 + Npad_v;
    int*   pi = (int*)(pd + np2);
    sqnorm_kernel<<<dim3(Npad_v / 16), dim3(256), 0, stream>>>(tg, t2, N, Npad_v);
    knn_partial_kernel<<<dim3(CH, B / QB), dim3(BLK), 0, stream>>>(x, tg, t2, pd, pi, N);
    merge_kernel_f<<<dim3(B), dim3(64), 0, stream>>>(tg, pd, pi, out, CH);
  } else {
    knn_fallback<<<dim3(B), dim3(256), 0, stream>>>(x, tg, out, N);
  }
}

// Round 13
// 97.579 us; speedup vs baseline: 2.7757x; 1.0114x over previous
//
#include <hip/hip_runtime.h>

// KNN (k=5, LARGEST distances per faithful-to-source quirk) + gather-mean.
// x: [B=2048, 64] f32, target: [N=50000, 64] f32, out: [B, 64] f32.
//
// Tier-1 (MFMA): distance GEMM via f16 hi/lo split:
//   x = hi + lo*2^-12 (lo pre-scaled by 2^12, f16-normal)
//   dot ~= hh + 2^-12*(hl + lh)
// Selection key: v = dot - t2/2 (min == farthest), SIGN-AWARE monotone-mapped
// to u32 (u ^ (asr(u,31)|0x80000000)) with the wave-uniform tile counter j in
// the cleared low 6-7 mantissa bits. Key quantum ~2^-11 abs (|v|~30-90,
// exponent 2^5-2^6) — proven absmax=0 in r10/r11. [r12 ERRATA: a +1024
// positivity shift inflated the exponent to 2^10 -> quantum 2^-7 -> flipped
// real neighbors (absmax 0.836). Key quantum is exponent-dependent; keep |v|
// small.] Top-5 = 9-op v_min_u32/v_max_u32 insertion network (r10's decisive
// lever, 257us -> 100us). Kernel-B shape = r10's proven config (256 thr,
// GT=2, CHN=64: VALUBusy 72%); prep fused (r11: overhead 6.8 -> 4.2us).

typedef _Float16 f16x8 __attribute__((ext_vector_type(8)));
typedef float    f32x4 __attribute__((ext_vector_type(4)));

constexpr int KNN = 5;
constexpr int DD  = 64;    // feature dim
constexpr int NTT = 16;    // targets per MFMA tile
constexpr int GT  = 2;     // tiles per phase (16KB LDS dbuf)
constexpr int QBB = 64;    // queries per block (4 waves x 16)

// tier-2 (VALU) constants — round-3 kernel kept as fallback
constexpr int TQ  = 4;
constexpr int QB  = 32;
constexpr int NT  = 256;
constexpr int KC  = 16;
constexpr int CH  = 16;
constexpr int BLK = 512;

__device__ __forceinline__ bool pair_gt(float ad, int ai, float bd, int bi) {
  return (ad > bd) || (ad == bd && ai < bi);
}
__device__ __forceinline__ bool pair_lt_u(unsigned ad, int ai, unsigned bd, int bi) {
  return (ad < bd) || (ad == bd && ai < bi);
}

// max-semantics sorted insert (tier-2/3 paths)
__device__ __forceinline__ void top5_insert(float d2, int idx,
    float& t0d, float& t1d, float& t2d, float& t3d, float& t4d,
    int&   t0i, int&   t1i, int&   t2i, int&   t3i, int&   t4i) {
  const bool b3 = pair_gt(d2, idx, t3d, t3i);
  const bool b2 = pair_gt(d2, idx, t2d, t2i);
  const bool b1 = pair_gt(d2, idx, t1d, t1i);
  const bool b0 = pair_gt(d2, idx, t0d, t0i);
  t4d = b3 ? t3d : d2;               t4i = b3 ? t3i : idx;
  t3d = b3 ? (b2 ? t2d : d2) : t3d;  t3i = b3 ? (b2 ? t2i : idx) : t3i;
  t2d = b2 ? (b1 ? t1d : d2) : t2d;  t2i = b2 ? (b1 ? t1i : idx) : t2i;
  t1d = b1 ? (b0 ? t0d : d2) : t1d;  t1i = b1 ? (b0 ? t0i : idx) : t1i;
  t0d = b0 ? d2 : t0d;               t0i = b0 ? idx : t0i;
}

// 9-op min/max insertion into ascending sorted 5 (tier-1 hot path, u32 keys)
__device__ __forceinline__ void ins5_u32(unsigned c,
    unsigned& a0, unsigned& a1, unsigned& a2, unsigned& a3, unsigned& a4) {
  unsigned t;
  t = min(a0, c); c = max(a0, c); a0 = t;
  t = min(a1, c); c = max(a1, c); a1 = t;
  t = min(a2, c); c = max(a2, c); a2 = t;
  t = min(a3, c); c = max(a3, c); a3 = t;
  a4 = min(a4, c);
}

__device__ __forceinline__ void gload16(const void* g, void* l) {
  __builtin_amdgcn_global_load_lds(
      (const __attribute__((address_space(1))) unsigned int*)g,
      (__attribute__((address_space(3))) unsigned int*)l, 16, 0, 0);
}

// ------- Kernel A (tier-1, fused): f16 hi/lo tile image + bias image -------
// tcvt per tile (4096B): [term(2)][kb(8)][col(16)][i(8)] f16; k = kb*8+i.
// t2c[ci][j][col] = -||t||^2/2 (pad rows +1e30), chunk-contiguous.
__launch_bounds__(256)
__global__ void prep_kernel(const float* __restrict__ tg,
                            unsigned short* __restrict__ tcvt,
                            float* __restrict__ t2c,
                            int N, int TT, int tiles, int chnlog) {
  const int tid  = threadIdx.x;
  const int lane = tid & 63;
  const int w    = __builtin_amdgcn_readfirstlane(tid >> 6);
  const int t    = blockIdx.x * 4 + w;          // tile index
  if (t >= TT) return;
  const int col   = lane & 15;
  const int khalf = lane >> 4;                  // 0..3
  const int row   = t * NTT + col;              // global target row
  float ss = 0.0f;
  #pragma unroll
  for (int j = 0; j < 2; ++j) {
    const int kb = khalf * 2 + j;               // 0..7
    float v[8];
    if (row < N) {
      const float4 a = *reinterpret_cast<const float4*>(tg + (size_t)row * DD + kb * 8);
      const float4 b = *reinterpret_cast<const float4*>(tg + (size_t)row * DD + kb * 8 + 4);
      v[0]=a.x; v[1]=a.y; v[2]=a.z; v[3]=a.w;
      v[4]=b.x; v[5]=b.y; v[6]=b.z; v[7]=b.w;
    } else {
      #pragma unroll
      for (int i = 0; i < 8; ++i) v[i] = 0.0f;
    }
    f16x8 hv, lv;
    #pragma unroll
    for (int i = 0; i < 8; ++i) {
      const _Float16 h = (_Float16)v[i];
      hv[i] = h;
      lv[i] = (_Float16)((v[i] - (float)h) * 4096.0f);
      ss = fmaf(v[i], v[i], ss);
    }
    const size_t off = (size_t)t * 2048 + kb * 128 + col * 8;  // ushort units
    *reinterpret_cast<f16x8*>(tcvt + off)        = hv;
    *reinterpret_cast<f16x8*>(tcvt + off + 1024) = lv;
  }
  // row-norm: reduce across the 4 lanes sharing this col (lane bits 4,5)
  ss += __shfl_xor(ss, 16);
  ss += __shfl_xor(ss, 32);
  if (khalf == 0) {
    const float bias = (row < N) ? -0.5f * ss : 1e30f;
    const int ci = t & ((1 << chnlog) - 1);
    const int jj = t >> chnlog;
    t2c[((size_t)ci * tiles + jj) * 16 + col] = bias;
  }
}

// ------- Kernel A (tier-2): linear sqnorm (pad rows -1e30) -------
__launch_bounds__(256)
__global__ void sqnorm_kernel(const float* __restrict__ tg,
                              float* __restrict__ t2, int N, int Npad) {
  const int tid  = threadIdx.x;
  const int lane = tid & 63;
  const int wv   = tid >> 6;
  const int row  = blockIdx.x * 16 + wv * 4 + (lane >> 4);
  const int f4   = lane & 15;
  if (row >= Npad) return;
  float s = -1e30f;
  if (row < N) {
    const float4 v = reinterpret_cast<const float4*>(tg)[(size_t)row * 16 + f4];
    s = v.x*v.x + v.y*v.y + v.z*v.z + v.w*v.w;
    s += __shfl_xor(s, 1);
    s += __shfl_xor(s, 2);
    s += __shfl_xor(s, 4);
    s += __shfl_xor(s, 8);
  }
  if (f4 == 0) t2[row] = s;
}

// ---------------- Kernel B (MFMA): distances + per-(query,chunk) bottom-5 ----------------
#define MFMA16(A, B, C) __builtin_amdgcn_mfma_f32_16x16x32_f16((A), (B), (C), 0, 0, 0)

__launch_bounds__(256)
__global__ void knn_mfma_kernel(const float* __restrict__ x,
                                const unsigned short* __restrict__ tcvt,
                                const float* __restrict__ t2c,
                                unsigned* __restrict__ pdu,
                                int*      __restrict__ pi,
                                int tiles, int CHN, unsigned jmask) {
  __shared__ unsigned short sbuf[2][GT * 2048];  // 16 KiB, double-buffered

  const int tid  = threadIdx.x;
  const int lane = tid & 63;
  const int w    = __builtin_amdgcn_readfirstlane(tid >> 6);
  const int ci   = blockIdx.x;                  // target chunk
  const int q0w  = blockIdx.y * QBB + w * 16;   // wave's first query
  const int col  = lane & 15;
  const int kb   = lane >> 4;                   // 0..3
  const unsigned kclear = ~jmask;

  // ---- A fragments: 16 queries x 64 d, f16 hi/lo, in regs all kernel ----
  f16x8 ah[2], al[2];
  #pragma unroll
  for (int c = 0; c < 2; ++c) {
    const float* xp = x + (size_t)(q0w + col) * DD + c * 32 + kb * 8;
    const float4 a = *reinterpret_cast<const float4*>(xp);
    const float4 b = *reinterpret_cast<const float4*>(xp + 4);
    float v[8] = {a.x, a.y, a.z, a.w, b.x, b.y, b.z, b.w};
    #pragma unroll
    for (int i = 0; i < 8; ++i) {
      const _Float16 h = (_Float16)v[i];
      ah[c][i] = h;
      al[c][i] = (_Float16)((v[i] - (float)h) * 4096.0f);
    }
  }

  // per-lane bottom-5 packed keys per C-reg slot (4 queries/lane), ascending
  unsigned k0[4], k1[4], k2[4], k3[4], k4[4];
  #pragma unroll
  for (int r = 0; r < 4; ++r) {
    k0[r]=k1[r]=k2[r]=k3[r]=k4[r] = 0xFFFFFFFFu;
  }

  const int NP = tiles / GT;                    // exact (tiles % GT == 0)

  // running pointers
  const size_t tstep = (size_t)CHN * 2048;      // ushorts per j-step
  const unsigned short* gsrc = tcvt + (size_t)ci * 2048 + tid * 8;
  const float* tp  = t2c + (size_t)ci * tiles * 16 + col;

  // ---- prologue: stage phase 0 + bias ----
  #pragma unroll
  for (int g = 0; g < GT; ++g)
    gload16(gsrc + (size_t)g * tstep, &sbuf[0][g * 2048 + tid * 8]);
  float t2cur[GT], t2nxt[GT];
  #pragma unroll
  for (int g = 0; g < GT; ++g) t2cur[g] = tp[g * 16];
  __syncthreads();

  const unsigned short* gp = gsrc + (size_t)GT * tstep;  // phase p+1 tiles
  const float* tpr = tp + GT * 16;                       // phase p+1 bias
  const int lbase = kb * 128 + col * 8;                  // ushort offset of lane frag

  for (int p = 0; p < NP; ++p) {
    const int bp = p & 1;
    // 1) stage phase p+1
    if (p + 1 < NP) {
      #pragma unroll
      for (int g = 0; g < GT; ++g)
        gload16(gp + (size_t)g * tstep, &sbuf[bp ^ 1][g * 2048 + tid * 8]);
      #pragma unroll
      for (int g = 0; g < GT; ++g) t2nxt[g] = tpr[g * 16];
    }
    // 2) compute phase p (GT uniform tiles, 6 MFMA each)
    #pragma unroll
    for (int g = 0; g < GT; ++g) {
      const unsigned jt = (unsigned)(p * GT + g);        // wave-uniform tile ctr
      const unsigned short* tb = &sbuf[bp][g * 2048];
      const f16x8 bh0 = *reinterpret_cast<const f16x8*>(tb + lbase);
      const f16x8 bh1 = *reinterpret_cast<const f16x8*>(tb + lbase + 512);
      const f16x8 bl0 = *reinterpret_cast<const f16x8*>(tb + lbase + 1024);
      const f16x8 bl1 = *reinterpret_cast<const f16x8*>(tb + lbase + 1536);
      const float hv = t2cur[g];                // pre-scaled -t2/2
      f32x4 acc1 = {hv, hv, hv, hv};
      f32x4 acc2 = {0.f, 0.f, 0.f, 0.f};
      acc1 = MFMA16(ah[0], bh0, acc1);
      acc1 = MFMA16(ah[1], bh1, acc1);
      acc2 = MFMA16(ah[0], bl0, acc2);
      acc2 = MFMA16(ah[1], bl1, acc2);
      acc2 = MFMA16(al[0], bh0, acc2);
      acc2 = MFMA16(al[1], bh1, acc2);
      #pragma unroll
      for (int r = 0; r < 4; ++r) {
        const float v = fmaf(acc2[r], 0x1p-12f, acc1[r]);  // v = dot - t2/2
        const unsigned u = __float_as_uint(v);
        const unsigned m = (unsigned)((int)u >> 31) | 0x80000000u;  // monotone map
        const unsigned key = ((u ^ m) & kclear) | jt;
        ins5_u32(key, k0[r], k1[r], k2[r], k3[r], k4[r]);
      }
    }
    #pragma unroll
    for (int g = 0; g < GT; ++g) t2cur[g] = t2nxt[g];
    gp  += (size_t)GT * tstep;
    tpr += GT * 16;
    __syncthreads();
  }

  // ---- merge within each 16-lane group (cold): (key, exact idx) lex merge ----
  const int ibase = ci * 16 + col;
  const int istep = CHN * 16;
  #pragma unroll
  for (int r = 0; r < 4; ++r) {
    unsigned rd[KNN]; int ri[KNN];
    #pragma unroll
    for (int rr = 0; rr < KNN; ++rr) {
      const int head_i = (int)(k0[r] & jmask) * istep + ibase;
      unsigned md = k0[r]; int mi = head_i;
      #pragma unroll
      for (int k = 1; k < 16; k <<= 1) {
        const unsigned od = __shfl_xor(md, k);
        const int      oi = __shfl_xor(mi, k);
        if (pair_lt_u(od, oi, md, mi)) { md = od; mi = oi; }
      }
      rd[rr] = md; ri[rr] = mi;
      if (k0[r] == md && head_i == mi) {        // consume own head
        k0[r]=k1[r]; k1[r]=k2[r]; k2[r]=k3[r]; k3[r]=k4[r]; k4[r]=0xFFFFFFFFu;
      }
    }
    if (col == 0) {
      const int q = q0w + (lane >> 4) * 4 + r;
      const int pbase = q * (CHN * KNN) + ci * KNN;
      #pragma unroll
      for (int rr = 0; rr < KNN; ++rr) { pdu[pbase + rr] = rd[rr]; pi[pbase + rr] = ri[rr]; }
    }
  }
}

// ------- Kernel C (tier-1): unsigned-key merge of partials, gather, mean -------
__launch_bounds__(64)
__global__ void merge_kernel_u(const float* __restrict__ tg,
                               const unsigned* __restrict__ pdu,
                               const int*      __restrict__ pi,
                               float* __restrict__ out, int chn) {
  const int q    = blockIdx.x;
  const int lane = threadIdx.x;   // 64 threads
  const int M    = chn * KNN;     // up to 320 candidates
  const int pb   = q * M;
  unsigned cd[5]; int cix[5];
  #pragma unroll
  for (int s = 0; s < 5; ++s) {
    const int i = lane + s * 64;
    const bool v = i < M;
    cd[s]  = v ? pdu[pb + i] : 0xFFFFFFFFu;
    cix[s] = v ? pi[pb + i] : 0x7FFFFFFF;
  }
  int sel[KNN];
  #pragma unroll
  for (int r = 0; r < KNN; ++r) {
    unsigned md = cd[0]; int mi = cix[0];
    #pragma unroll
    for (int s = 1; s < 5; ++s)
      if (pair_lt_u(cd[s], cix[s], md, mi)) { md = cd[s]; mi = cix[s]; }
    #pragma unroll
    for (int k = 1; k < 64; k <<= 1) {
      const unsigned od = __shfl_xor(md, k);
      const int      oi = __shfl_xor(mi, k);
      if (pair_lt_u(od, oi, md, mi)) { md = od; mi = oi; }
    }
    sel[r] = mi;
    #pragma unroll
    for (int s = 0; s < 5; ++s)
      if (cd[s] == md && cix[s] == mi) { cd[s] = 0xFFFFFFFFu; cix[s] = 0x7FFFFFFF; }
  }
  float s = 0.0f;
  #pragma unroll
  for (int r = 0; r < KNN; ++r) s += tg[(size_t)sel[r] * DD + lane];
  out[(size_t)q * DD + lane] = s / 5.0f;
}

// ------- Kernel C (tier-2/3): float merge (unchanged) -------
__launch_bounds__(64)
__global__ void merge_kernel_f(const float* __restrict__ tg,
                               const float* __restrict__ pd,
                               const int*   __restrict__ pi,
                               float* __restrict__ out, int chn) {
  const int q    = blockIdx.x;
  const int lane = threadIdx.x;
  const int M    = chn * KNN;
  const int pb   = q * M;
  float cd[5]; int cix[5];
  #pragma unroll
  for (int s = 0; s < 5; ++s) {
    const int i = lane + s * 64;
    const bool v = i < M;
    cd[s]  = v ? pd[pb + i] : -1e30f;
    cix[s] = v ? pi[pb + i] : 0;
  }
  int sel[KNN];
  #pragma unroll
  for (int r = 0; r < KNN; ++r) {
    float md = cd[0]; int mi = cix[0];
    #pragma unroll
    for (int s = 1; s < 5; ++s)
      if (pair_gt(cd[s], cix[s], md, mi)) { md = cd[s]; mi = cix[s]; }
    #pragma unroll
    for (int k = 1; k < 64; k <<= 1) {
      const float od = __shfl_xor(md, k);
      const int   oi = __shfl_xor(mi, k);
      if (pair_gt(od, oi, md, mi)) { md = od; mi = oi; }
    }
    sel[r] = mi;
    #pragma unroll
    for (int s = 0; s < 5; ++s)
      if (cix[s] == mi && cd[s] == md) cd[s] = -1e30f;
  }
  float s = 0.0f;
  #pragma unroll
  for (int r = 0; r < KNN; ++r) s += tg[(size_t)sel[r] * DD + lane];
  out[(size_t)q * DD + lane] = s / 5.0f;
}

// ---------------- Tier-2 (round-3 VALU kernel, fallback if ws too small) ----------------
__launch_bounds__(BLK)
__global__ void knn_partial_kernel(const float* __restrict__ x,
                                   const float* __restrict__ tg,
                                   const float* __restrict__ t2w,
                                   float* __restrict__ pd,
                                   int*   __restrict__ pi,
                                   int N) {
  __shared__ float tbuf[2][KC][NT];

  const int tid  = threadIdx.x;
  const int lane = tid & 63;
  const int w    = __builtin_amdgcn_readfirstlane(tid >> 6);
  const int ci   = blockIdx.x;
  const int q0   = blockIdx.y * QB + w * TQ;
  const float* xq = x + (size_t)q0 * DD;

  float td0[TQ], td1[TQ], td2[TQ], td3[TQ], td4[TQ];
  int   ti0[TQ], ti1[TQ], ti2[TQ], ti3[TQ], ti4[TQ];
  #pragma unroll
  for (int qi = 0; qi < TQ; ++qi) {
    td0[qi]=td1[qi]=td2[qi]=td3[qi]=td4[qi] = -1e30f;
    ti0[qi]=ti1[qi]=ti2[qi]=ti3[qi]=ti4[qi] = 0;
  }

  float acc[TQ][4];
  const int total_tiles = (N + NT - 1) / NT;
  const int mytiles = (ci < total_tiles) ? ((total_tiles - 1 - ci) / CH + 1) : 0;
  const int C = mytiles * 4;

  float4 sva = make_float4(0,0,0,0), svb = make_float4(0,0,0,0);
  const int n0  = tid & 255;
  const int j40 = tid >> 8;
  const int j41 = j40 + 2;
  const float4* tgv = reinterpret_cast<const float4*>(tg);

  if (C > 0) {
    const long r0 = (long)ci * NT + n0;
    if (r0 < N) { sva = tgv[r0 * 16 + j40]; svb = tgv[r0 * 16 + j41]; }
    tbuf[0][j40*4+0][n0] = sva.x;  tbuf[0][j40*4+1][n0] = sva.y;
    tbuf[0][j40*4+2][n0] = sva.z;  tbuf[0][j40*4+3][n0] = sva.w;
    tbuf[0][j41*4+0][n0] = svb.x;  tbuf[0][j41*4+1][n0] = svb.y;
    tbuf[0][j41*4+2][n0] = svb.z;  tbuf[0][j41*4+3][n0] = svb.w;
  }
  __syncthreads();

  for (int c = 0; c < C; ++c) {
    const int b       = c & 1;
    const int kc      = c & 3;
    const int tileidx = ci + (c >> 2) * CH;
    const bool more   = (c + 1 < C);

    if (more) {
      const int gc2   = c + 1;
      const int kc2   = gc2 & 3;
      const int tile2 = ci + (gc2 >> 2) * CH;
      const long r0n  = (long)tile2 * NT + n0;
      sva = make_float4(0,0,0,0);
      svb = make_float4(0,0,0,0);
      if (r0n < N) {
        sva = tgv[r0n * 16 + kc2 * 4 + j40];
        svb = tgv[r0n * 16 + kc2 * 4 + j41];
      }
    }

    if (kc == 0) {
      #pragma unroll
      for (int qi = 0; qi < TQ; ++qi) {
        acc[qi][0]=0.f; acc[qi][1]=0.f; acc[qi][2]=0.f; acc[qi][3]=0.f;
      }
    }
    #pragma unroll
    for (int h = 0; h < 2; ++h) {
      const int dbase = kc * KC + h * 8;
      float qs[TQ][8];
      #pragma unroll
      for (int qi = 0; qi < TQ; ++qi) {
        const float4 qa = *reinterpret_cast<const float4*>(xq + qi * DD + dbase);
        const float4 qb = *reinterpret_cast<const float4*>(xq + qi * DD + dbase + 4);
        qs[qi][0]=qa.x; qs[qi][1]=qa.y; qs[qi][2]=qa.z; qs[qi][3]=qa.w;
        qs[qi][4]=qb.x; qs[qi][5]=qb.y; qs[qi][6]=qb.z; qs[qi][7]=qb.w;
      }
      #pragma unroll
      for (int dd = 0; dd < 8; ++dd) {
        const float4 tv = *reinterpret_cast<const float4*>(&tbuf[b][h*8+dd][lane*4]);
        #pragma unroll
        for (int qi = 0; qi < TQ; ++qi) {
          acc[qi][0] = fmaf(qs[qi][dd], tv.x, acc[qi][0]);
          acc[qi][1] = fmaf(qs[qi][dd], tv.y, acc[qi][1]);
          acc[qi][2] = fmaf(qs[qi][dd], tv.z, acc[qi][2]);
          acc[qi][3] = fmaf(qs[qi][dd], tv.w, acc[qi][3]);
        }
      }
    }

    if (kc == 3) {
      const int nb = tileidx * NT + lane * 4;
      const float4 t2v = *reinterpret_cast<const float4*>(t2w + nb);
      const float t2a[4] = { t2v.x, t2v.y, t2v.z, t2v.w };
      #pragma unroll
      for (int qi = 0; qi < TQ; ++qi) {
        #pragma unroll
        for (int j = 0; j < 4; ++j) {
          const float r2  = fmaf(-2.0f, acc[qi][j], t2a[j]);
          const int   idx = nb + j;
          if (idx < N && pair_gt(r2, idx, td4[qi], ti4[qi]))
            top5_insert(r2, idx,
                        td0[qi], td1[qi], td2[qi], td3[qi], td4[qi],
                        ti0[qi], ti1[qi], ti2[qi], ti3[qi], ti4[qi]);
        }
      }
    }

    if (more) {
      const int bo = (c + 1) & 1;
      tbuf[bo][j40*4+0][n0] = sva.x;  tbuf[bo][j40*4+1][n0] = sva.y;
      tbuf[bo][j40*4+2][n0] = sva.z;  tbuf[bo][j40*4+3][n0] = sva.w;
      tbuf[bo][j41*4+0][n0] = svb.x;  tbuf[bo][j41*4+1][n0] = svb.y;
      tbuf[bo][j41*4+2][n0] = svb.z;  tbuf[bo][j41*4+3][n0] = svb.w;
    }
    __syncthreads();
  }

  #pragma unroll
  for (int qi = 0; qi < TQ; ++qi) {
    float rd[KNN]; int ri[KNN];
    #pragma unroll
    for (int r = 0; r < KNN; ++r) {
      float md = td0[qi]; int mi = ti0[qi];
      #pragma unroll
      for (int k = 1; k < 64; k <<= 1) {
        const float od = __shfl_xor(md, k);
        const int   oi = __shfl_xor(mi, k);
        if (pair_gt(od, oi, md, mi)) { md = od; mi = oi; }
      }
      rd[r] = md; ri[r] = mi;
      if (ti0[qi] == mi && td0[qi] == md) {
        td0[qi]=td1[qi]; ti0[qi]=ti1[qi];
        td1[qi]=td2[qi]; ti1[qi]=ti2[qi];
        td2[qi]=td3[qi]; ti2[qi]=ti3[qi];
        td3[qi]=td4[qi]; ti3[qi]=ti4[qi];
        td4[qi]=-1e30f;  ti4[qi]=0;
      }
    }
    if (lane == 0) {
      const int pbase = (q0 + qi) * (CH * KNN) + ci * KNN;
      #pragma unroll
      for (int r = 0; r < KNN; ++r) { pd[pbase + r] = rd[r]; pi[pbase + r] = ri[r]; }
    }
  }
}

// ---------------- Tier-3 fallback ----------------
__launch_bounds__(256)
__global__ void knn_fallback(const float* __restrict__ x,
                             const float* __restrict__ tg,
                             float* __restrict__ out, int N) {
  const int q   = blockIdx.x;
  const int tid = threadIdx.x;
  __shared__ float qsh[DD];
  __shared__ float smd[KNN][256];
  __shared__ int   smi[KNN][256];
  if (tid < DD) qsh[tid] = x[(size_t)q * DD + tid];
  __syncthreads();
  float qv[DD];
  #pragma unroll
  for (int d = 0; d < DD; ++d) qv[d] = qsh[d];
  float x2 = 0.0f;
  #pragma unroll
  for (int d = 0; d < DD; ++d) x2 = fmaf(qv[d], qv[d], x2);
  float a0=-1e30f,a1=-1e30f,a2=-1e30f,a3=-1e30f,a4=-1e30f;
  int   i0=0,i1=0,i2=0,i3=0,i4=0;
  for (int n = tid; n < N; n += 256) {
    const float4* tr = reinterpret_cast<const float4*>(tg + (size_t)n * DD);
    float dot = 0.0f, tt = 0.0f;
    #pragma unroll
    for (int k = 0; k < 16; ++k) {
      const float4 tv = tr[k];
      dot = fmaf(qv[4*k+0], tv.x, dot); tt = fmaf(tv.x, tv.x, tt);
      dot = fmaf(qv[4*k+1], tv.y, dot); tt = fmaf(tv.y, tv.y, tt);
      dot = fmaf(qv[4*k+2], tv.z, dot); tt = fmaf(tv.z, tv.z, tt);
      dot = fmaf(qv[4*k+3], tv.w, dot); tt = fmaf(tv.w, tv.w, tt);
    }
    const float d2 = fmaf(-2.0f, dot, x2 + tt);
    if (pair_gt(d2, n, a4, i4))
      top5_insert(d2, n, a0,a1,a2,a3,a4, i0,i1,i2,i3,i4);
  }
  smd[0][tid]=a0; smi[0][tid]=i0;  smd[1][tid]=a1; smi[1][tid]=i1;
  smd[2][tid]=a2; smi[2][tid]=i2;  smd[3][tid]=a3; smi[3][tid]=i3;
  smd[4][tid]=a4; smi[4][tid]=i4;
  __syncthreads();
  if (tid < 64) {
    a0=a1=a2=a3=a4=-1e30f; i0=i1=i2=i3=i4=0;
    for (int src = tid; src < 256; src += 64) {
      #pragma unroll
      for (int r = 0; r < KNN; ++r) {
        const float dd2 = smd[r][src]; const int ii = smi[r][src];
        if (pair_gt(dd2, ii, a4, i4))
          top5_insert(dd2, ii, a0,a1,a2,a3,a4, i0,i1,i2,i3,i4);
      }
    }
    int sel[KNN];
    #pragma unroll
    for (int r = 0; r < KNN; ++r) {
      float md = a0; int mi = i0;
      #pragma unroll
      for (int k = 1; k < 64; k <<= 1) {
        const float od = __shfl_xor(md, k);
        const int   oi = __shfl_xor(mi, k);
        if (pair_gt(od, oi, md, mi)) { md = od; mi = oi; }
      }
      sel[r] = mi;
      if (i0 == mi && a0 == md) {
        a0=a1; i0=i1; a1=a2; i1=i2; a2=a3; i2=i3; a3=a4; i3=i4; a4=-1e30f; i4=0;
      }
    }
    float s = 0.0f;
    #pragma unroll
    for (int r = 0; r < KNN; ++r) s += tg[(size_t)sel[r] * DD + tid];
    out[(size_t)q * DD + tid] = s / 5.0f;
  }
}

extern "C" void kernel_launch(void* const* d_in, const int* in_sizes, int n_in,
                              void* d_out, int out_size, void* d_ws, size_t ws_size,
                              hipStream_t stream) {
  const float* x  = (const float*)d_in[0];
  const float* tg = (const float*)d_in[1];
  float* out = (float*)d_out;
  const int B = in_sizes[0] / DD;   // 2048
  const int N = in_sizes[1] / DD;   // 50000

  // tier-1: Npad multiple of CHN*GT*16 for fully uniform loops
  auto t1_need = [&](int chn, int& npad, int& tt, int& tiles) {
    const int align = chn * GT * NTT;
    npad  = ((N + align - 1) / align) * align;
    tt    = npad / NTT;
    tiles = tt / chn;
    return (size_t)npad * 4 + (size_t)B * chn * KNN * 8 + (size_t)tt * 4096;
  };
  int Npad64, TT64, tiles64, Npad32, TT32, tiles32;
  const size_t need64 = t1_need(64, Npad64, TT64, tiles64);
  const size_t need32 = t1_need(32, Npad32, TT32, tiles32);

  int CHN = 0, Npad = 0, TT = 0, tiles = 0, chnlog = 0;
  unsigned jmask = 63;
  if (ws_size >= need64)      { CHN = 64; Npad = Npad64; TT = TT64; tiles = tiles64; chnlog = 6; jmask = 63;  }
  else if (ws_size >= need32) { CHN = 32; Npad = Npad32; TT = TT32; tiles = tiles32; chnlog = 5; jmask = 127; }

  if (CHN > 0 && (B % QBB) == 0 && tiles <= (int)jmask + 1) {
    const size_t np1 = (size_t)B * CHN * KNN;
    float*          t2c  = (float*)d_ws;
    unsigned*       pdu  = (unsigned*)(t2c + Npad);
    int*            pi   = (int*)(pdu + np1);
    unsigned short* tcvt = (unsigned short*)(pi + np1);
    prep_kernel<<<dim3((TT + 3) / 4), dim3(256), 0, stream>>>(tg, tcvt, t2c, N, TT, tiles, chnlog);
    knn_mfma_kernel<<<dim3(CHN, B / QBB), dim3(256), 0, stream>>>(x, tcvt, t2c, pdu, pi, tiles, CHN, jmask);
    merge_kernel_u<<<dim3(B), dim3(64), 0, stream>>>(tg, pdu, pi, out, CHN);
    return;
  }

  // tier-2
  const int    Npad_v    = (N + NT - 1) & ~(NT - 1);
  const size_t np2       = (size_t)B * CH * KNN;
  const size_t need_valu = ((size_t)Npad_v + 2 * np2) * 4;
  if (ws_size >= need_valu && (B % QB) == 0) {
    float* t2 = (float*)d_ws;
    float* pd = t2 + Npad_v;
    int*   pi = (int*)(pd + np2);
    sqnorm_kernel<<<dim3(Npad_v / 16), dim3(256), 0, stream>>>(tg, t2, N, Npad_v);
    knn_partial_kernel<<<dim3(CH, B / QB), dim3(BLK), 0, stream>>>(x, tg, t2, pd, pi, N);
    merge_kernel_f<<<dim3(B), dim3(64), 0, stream>>>(tg, pd, pi, out, CH);
  } else {
    knn_fallback<<<dim3(B), dim3(256), 0, stream>>>(x, tg, out, N);
  }
}